// Round 4
// baseline (197.924 us; speedup 1.0000x reference)
//
#include <hip/hip_runtime.h>
#include <cstdint>
#include <cstddef>

// ManualChebConv via Chebyshev composition, v4: occupancy (2 blocks/CU).
//   M2 := T2(L) = 2L^2 - I  (precomputed bf16, split-precision MFMA)
//   Round 1: Z1 = L@Z0 (pass), Z2 = M2@Z0 (pass)
//   Round 2: S3 = 2L@Z2, S4 = 2M2@Z2
//   out = Z0@(W0-W4) + Z1@(W1-W3) + Z2@W2 + S3@W3 + S4@W4 + b
//
// v4 change (post-mortem of v1-v3): time invariant under work reduction;
// all pipes <25% busy; occupancy pinned at 21% (133KB LDS -> 1 block/CU,
// 2 waves/SIMD; 8 full-CU barrier drains). Fix: BT=2 (2 batches/block),
// 512 blocks, 66.5KB LDS -> 2 blocks/CU -> 4 waves/SIMD; one block's compute
// fills the other's barrier/latency stalls. L/M2 passes made sequential
// (not fused) to fit the 128-VGPR budget of 4 waves/SIMD without spill.

typedef __attribute__((ext_vector_type(8))) short  frag_ab;  // 8 bf16
typedef __attribute__((ext_vector_type(4))) float  frag_cd;  // 4 fp32

constexpr int BN    = 512;        // N
constexpr int FIN   = 16;
constexpr int FOUT  = 8;
constexpr int LDST  = BN + 8;     // padded stride (bank-friendly, 16B aligned)

// v4 primary kernel: 2 batches per block
constexpr int BT2   = 2;
constexpr int NC2   = BT2 * FIN;      // 32 combined cols
constexpr int ZB2   = NC2 * LDST;     // 16,640 u16 = 33,280 B per buffer

// v1 fallback: 4 batches per block
constexpr int BT1   = 4;
constexpr int NC1   = BT1 * FIN;      // 64
constexpr int ZB1   = NC1 * LDST;     // 33,280 u16

__device__ __forceinline__ uint16_t f2bf(float f) {
    uint32_t u = __builtin_bit_cast(uint32_t, f);
    u += 0x7FFFu + ((u >> 16) & 1u);          // round-to-nearest-even
    return (uint16_t)(u >> 16);
}
__device__ __forceinline__ float bf2f(uint16_t h) {
    uint32_t u = ((uint32_t)h) << 16;
    return __builtin_bit_cast(float, u);
}

// Fragment-order index for an A-matrix element (row, k):
// fragment f = (row/16)*16 + (k/32); lane = ((k>>3)&3)*16 + (row&15); elem j = k&7.
__device__ __forceinline__ size_t aswz(int row, int k) {
    return ((size_t)((row >> 4) * 16 + (k >> 5)) * 64
            + ((k >> 3) & 3) * 16 + (row & 15)) * 8 + (k & 7);
}

// Row-major bf16 conversion (fallback path only)
__global__ void cvtL_rm(const float* __restrict__ Lf, uint16_t* __restrict__ Lb) {
    int i = blockIdx.x * 256 + threadIdx.x;   // 1024 x 256 = 262144
    Lb[i] = f2bf(Lf[i]);
}

// Swizzled bf16 conversion: thread t produces one lane-fragment (8 contiguous
// bf16 at output t*8). Output fully coalesced.
__global__ __launch_bounds__(256)
void cvtL_swz(const float* __restrict__ Lf, uint16_t* __restrict__ Lb) {
    int t = blockIdx.x * 256 + threadIdx.x;   // 128 x 256 = 32768
    int f = t >> 6, lane = t & 63;
    int mt = f >> 4, ks = f & 15;
    int row = mt * 16 + (lane & 15);
    int k0  = ks * 32 + (lane >> 4) * 8;
    const float4* p = reinterpret_cast<const float4*>(Lf + (size_t)row * BN + k0);
    float4 u0 = p[0], u1 = p[1];
    frag_ab o;
    o[0] = (short)f2bf(u0.x); o[1] = (short)f2bf(u0.y);
    o[2] = (short)f2bf(u0.z); o[3] = (short)f2bf(u0.w);
    o[4] = (short)f2bf(u1.x); o[5] = (short)f2bf(u1.y);
    o[6] = (short)f2bf(u1.z); o[7] = (short)f2bf(u1.w);
    *reinterpret_cast<frag_ab*>(Lb + (size_t)t * 8) = o;
}

// M2 = 2*L@L - I in bf16 (swizzled output), from fp32 L. Split-bf16 (hi/lo)
// MFMA: error ~ one bf16 rounding. L symmetric -> B[k][j] = L[j][k].
__global__ __launch_bounds__(256)
void m2comp(const float* __restrict__ Lf, uint16_t* __restrict__ Mb) {
    const int tid = threadIdx.x;
    const int wv = tid >> 6, lane = tid & 63, lr = lane & 15, q = lane >> 4;
    const int i0 = (blockIdx.x >> 4) * 32 + (wv >> 1) * 16;
    const int j0 = (blockIdx.x & 15) * 32 + (wv & 1) * 16;
    frag_cd acc = {0.f, 0.f, 0.f, 0.f};
    const float* arow = Lf + (size_t)(i0 + lr) * BN;   // A[m][k] = L[i0+m][k]
    const float* brow = Lf + (size_t)(j0 + lr) * BN;   // B[k][n] = L[j0+n][k]
    for (int ks = 0; ks < 16; ++ks) {
        const int kb = ks * 32 + q * 8;
        const float4* ap = reinterpret_cast<const float4*>(arow + kb);
        const float4* bp = reinterpret_cast<const float4*>(brow + kb);
        float4 a0 = ap[0], a1 = ap[1], b0 = bp[0], b1 = bp[1];
        float av[8]  = {a0.x, a0.y, a0.z, a0.w, a1.x, a1.y, a1.z, a1.w};
        float bvv[8] = {b0.x, b0.y, b0.z, b0.w, b1.x, b1.y, b1.z, b1.w};
        frag_ab ah, al, bh, bl;
#pragma unroll
        for (int j = 0; j < 8; ++j) {
            uint16_t h = f2bf(av[j]);
            ah[j] = (short)h;
            al[j] = (short)f2bf(av[j] - bf2f(h));
            uint16_t g = f2bf(bvv[j]);
            bh[j] = (short)g;
            bl[j] = (short)f2bf(bvv[j] - bf2f(g));
        }
        acc = __builtin_amdgcn_mfma_f32_16x16x32_bf16(ah, bh, acc, 0, 0, 0);
        acc = __builtin_amdgcn_mfma_f32_16x16x32_bf16(ah, bl, acc, 0, 0, 0);
        acc = __builtin_amdgcn_mfma_f32_16x16x32_bf16(al, bh, acc, 0, 0, 0);
    }
#pragma unroll
    for (int r = 0; r < 4; ++r) {
        int i = i0 + q * 4 + r, j = j0 + lr;
        float v = 2.f * acc[r] - ((i == j) ? 1.f : 0.f);
        Mb[aswz(i, j)] = f2bf(v);
    }
}

__global__ __launch_bounds__(512, 4)
void cheb2_kernel(const float* __restrict__ x, const uint16_t* __restrict__ Lb,
                  const uint16_t* __restrict__ Mb, const float* __restrict__ W,
                  const float* __restrict__ bvec, float* __restrict__ out) {
    __shared__ uint16_t lds[2 * ZB2];         // 66,560 B -> 2 blocks/CU
    uint16_t* z0 = lds;
    uint16_t* z1 = lds + ZB2;

    const int tid  = threadIdx.x;
    const int wave = tid >> 6;                // 0..7
    const int lane = tid & 63;
    const int lr   = lane & 15;
    const int q    = lane >> 4;

    // ---------------- stage x -> Z0^T (bf16) in z0 ----------------
    // 512 assignments (one per thread): (bl, f-chunk of 4, n-octet).
    const float4* x4 = reinterpret_cast<const float4*>(x + (size_t)blockIdx.x * (BT2 * BN * FIN));
    {
        int a   = tid;
        int f0g = a & 3;
        int n8  = (a >> 2) & 63;
        int bl  = a >> 8;                     // 0..1
        int jb  = bl * 2048 + n8 * 32 + f0g;
        float4 v[8];
#pragma unroll
        for (int r = 0; r < 8; ++r) v[r] = x4[jb + r * 4];
        int cb = bl * 16 + f0g * 4;
        int nb = n8 * 8;
#pragma unroll
        for (int w = 0; w < 4; ++w) {
            frag_ab pk;
#pragma unroll
            for (int r = 0; r < 8; ++r)
                pk[r] = (short)f2bf(reinterpret_cast<const float*>(&v[r])[w]);
            *reinterpret_cast<frag_ab*>(&z0[(cb + w) * LDST + nb]) = pk;
        }
    }

    // ---------------- combined W pair B-fragments + bias ----------------
    // Effective weights: E0=W0-W4, E1=W1-W3, E2=W2, E3=W3, E4=W4, E5=0.
    frag_ab wf[3];
#pragma unroll
    for (int p = 0; p < 3; ++p) {
        frag_ab t;
#pragma unroll
        for (int jj = 0; jj < 8; ++jj) {
            int k   = q * 8 + jj;
            int ki  = p * 2 + (k >> 4);
            int fin = k & 15;
            float val = 0.0f;
            if (lr < 8) {
                int idx = fin * FOUT + lr;
                if      (ki == 0) val = W[idx] - W[4 * (FIN * FOUT) + idx];
                else if (ki == 1) val = W[1 * (FIN * FOUT) + idx] - W[3 * (FIN * FOUT) + idx];
                else if (ki < 5)  val = W[ki * (FIN * FOUT) + idx];
            }
            t[jj] = (short)f2bf(val);
        }
        wf[p] = t;
    }
    const float bv = (lr < 8) ? bvec[lr] : 0.0f;

    frag_cd accOut[4][BT2] = {};              // [mtIdx][bt] out tiles (fp32)
    frag_cd acc[4][BT2];                      // single pass accumulator

    // One K-pass: acc = Amat @ cur  (A pre-swizzled: dense 1KB bursts)
    auto pass = [&](const uint16_t* Amat, const uint16_t* cur) {
#pragma unroll
        for (int mi = 0; mi < 4; ++mi)
#pragma unroll
            for (int ct = 0; ct < BT2; ++ct)
                acc[mi][ct] = (frag_cd){0.f, 0.f, 0.f, 0.f};
        for (int ks = 0; ks < 16; ++ks) {
            frag_ab bfr[BT2];
#pragma unroll
            for (int ct = 0; ct < BT2; ++ct)
                bfr[ct] = *reinterpret_cast<const frag_ab*>(
                    cur + (ct * 16 + lr) * LDST + ks * 32 + q * 8);
#pragma unroll
            for (int mi = 0; mi < 4; ++mi) {
                frag_ab a = *reinterpret_cast<const frag_ab*>(
                    Amat + ((size_t)((wave + mi * 8) * 16 + ks) * 64 + lane) * 8);
#pragma unroll
                for (int ct = 0; ct < BT2; ++ct)
                    acc[mi][ct] = __builtin_amdgcn_mfma_f32_16x16x32_bf16(
                        a, bfr[ct], acc[mi][ct], 0, 0, 0);
            }
        }
    };

    // Plain writeback: dst <- bf16(scale * acc)
    auto wb = [&](uint16_t* dst, float scale) {
#pragma unroll
        for (int mi = 0; mi < 4; ++mi) {
            int row0 = (wave + mi * 8) * 16 + q * 4;
#pragma unroll
            for (int ct = 0; ct < BT2; ++ct) {
                uint16_t* dp = dst + (ct * 16 + lr) * LDST + row0;
                ushort4 nv;
                nv.x = f2bf(scale * acc[mi][ct][0]);
                nv.y = f2bf(scale * acc[mi][ct][1]);
                nv.z = f2bf(scale * acc[mi][ct][2]);
                nv.w = f2bf(scale * acc[mi][ct][3]);
                *reinterpret_cast<ushort4*>(dp) = nv;
            }
        }
    };

    // Paired epilogue: accOut += [bufA | bufB](A-layout) @ wfr
    auto epi = [&](const uint16_t* bA, const uint16_t* bB, frag_ab wfr) {
        const uint16_t* base = (q < 2) ? bA : bB;
        int finb = (q & 1) * 8;
#pragma unroll
        for (int mi = 0; mi < 4; ++mi) {
            int n = (wave + mi * 8) * 16 + lr;
#pragma unroll
            for (int bt = 0; bt < BT2; ++bt) {
                const uint16_t* pp = base + (bt * 16 + finb) * LDST + n;
                frag_ab afr;
#pragma unroll
                for (int jj = 0; jj < 8; ++jj) afr[jj] = (short)pp[jj * LDST];
                accOut[mi][bt] = __builtin_amdgcn_mfma_f32_16x16x32_bf16(
                    afr, wfr, accOut[mi][bt], 0, 0, 0);
            }
        }
    };

    __syncthreads();                  // 2: z0 (Z0) visible
    pass(Lb, z0);                     // 3: acc = Z1 = L@Z0
    wb(z1, 1.f);                      // 4: z1 <- Z1 (z1 untouched so far: safe)
    __syncthreads();                  // 5: Z1 visible, passL z0-reads done
    epi(z0, z1, wf[0]);               // 6: accOut += Z0@(W0-W4) + Z1@(W1-W3)
    pass(Mb, z0);                     // 7: acc = Z2 = M2@Z0 (read-only on z0)
    __syncthreads();                  // 8: all z0 reads (epi0+passM) done
    wb(z0, 1.f);                      // 9: z0 <- Z2 (in-place over Z0)
    __syncthreads();                  // 10: Z2 visible
    pass(Lb, z0);                     // 11: acc = L@Z2
    wb(z1, 2.f);                      // 12: z1 <- S3 = 2L@Z2 (z1 dead since epi0, pre-barrier-8)
    __syncthreads();                  // 13: S3 visible, passL z0-reads done
    epi(z0, z1, wf[1]);               // 14: accOut += Z2@W2 + S3@W3
    pass(Mb, z0);                     // 15: acc = M2@Z2
    __syncthreads();                  // 16: all z0 reads done
    wb(z0, 2.f);                      // 17: z0 <- S4 = 2M2@Z2
    __syncthreads();                  // 18: S4 visible
    epi(z0, z0, wf[2]);               // 19: accOut += S4@W4 (second-half weights zero)

    // ---------------- store via LDS (dense float4 bursts) ----------------
    // z1 dead (last read epi1, pre-barrier-16). fbuf [bt][n][fo] fp32 = 32,768 B.
    float* fbuf = reinterpret_cast<float*>(z1);
    if (lr < 8) {
#pragma unroll
        for (int mi = 0; mi < 4; ++mi) {
            int n0 = (wave + mi * 8) * 16 + q * 4;
#pragma unroll
            for (int bt = 0; bt < BT2; ++bt) {
#pragma unroll
                for (int r = 0; r < 4; ++r)
                    fbuf[(bt * BN + n0 + r) * FOUT + lr] = accOut[mi][bt][r] + bv;
            }
        }
    }
    __syncthreads();
    {
        const float4* fb4 = reinterpret_cast<const float4*>(fbuf);
        float4* o4 = reinterpret_cast<float4*>(out + (size_t)blockIdx.x * (BT2 * BN * FOUT));
#pragma unroll
        for (int i = 0; i < 4; ++i)
            o4[i * 512 + tid] = fb4[i * 512 + tid];
    }
}

// ---------------- v1 fallback (4-app recurrence), used if ws too small ----------------
template <bool LBF16>
__global__ __launch_bounds__(512, 2)
void cheb1_kernel(const float* __restrict__ x, const float* __restrict__ Lf,
                  const uint16_t* __restrict__ Lb, const float* __restrict__ W,
                  const float* __restrict__ bvec, float* __restrict__ out) {
    __shared__ uint16_t lds[2 * ZB1];
    uint16_t* z0 = lds;
    uint16_t* z1 = lds + ZB1;

    const int tid  = threadIdx.x;
    const int wave = tid >> 6;
    const int lane = tid & 63;
    const int lr   = lane & 15;
    const int q    = lane >> 4;

    const float4* x4 = reinterpret_cast<const float4*>(x + (size_t)blockIdx.x * (BT1 * BN * FIN));
    for (int s = 0; s < 2; ++s) {
        int a   = tid + s * 512;
        int f0g = a & 3;
        int n8  = (a >> 2) & 63;
        int bl  = a >> 8;
        int jb  = bl * 2048 + n8 * 32 + f0g;
        float4 v[8];
#pragma unroll
        for (int r = 0; r < 8; ++r) v[r] = x4[jb + r * 4];
        int cb = bl * 16 + f0g * 4;
        int nb = n8 * 8;
#pragma unroll
        for (int w = 0; w < 4; ++w) {
            frag_ab pk;
#pragma unroll
            for (int r = 0; r < 8; ++r)
                pk[r] = (short)f2bf(reinterpret_cast<const float*>(&v[r])[w]);
            *reinterpret_cast<frag_ab*>(&z0[(cb + w) * LDST + nb]) = pk;
        }
    }

    frag_ab wf[3];
#pragma unroll
    for (int p = 0; p < 3; ++p) {
        frag_ab t;
#pragma unroll
        for (int jj = 0; jj < 8; ++jj) {
            int k   = q * 8 + jj;
            int ki  = p * 2 + (k >> 4);
            int fin = k & 15;
            float val = (lr < 8 && ki < 5) ? W[ki * (FIN * FOUT) + fin * FOUT + lr] : 0.0f;
            t[jj] = (short)f2bf(val);
        }
        wf[p] = t;
    }
    const float bv = (lr < 8) ? bvec[lr] : 0.0f;

    frag_cd accOut[4][4] = {};

    auto loadA = [&](int mt, int ks) -> frag_ab {
        int row = mt * 16 + lr;
        int kb  = ks * 32 + q * 8;
        if constexpr (LBF16) {
            return *reinterpret_cast<const frag_ab*>(Lb + row * BN + kb);
        } else {
            const float4* p  = reinterpret_cast<const float4*>(Lf + row * BN + kb);
            float4 u0 = p[0], u1 = p[1];
            frag_ab t;
            t[0] = (short)f2bf(u0.x); t[1] = (short)f2bf(u0.y);
            t[2] = (short)f2bf(u0.z); t[3] = (short)f2bf(u0.w);
            t[4] = (short)f2bf(u1.x); t[5] = (short)f2bf(u1.y);
            t[6] = (short)f2bf(u1.z); t[7] = (short)f2bf(u1.w);
            return t;
        }
    };

    auto app = [&](const uint16_t* cur, uint16_t* dst, bool first) {
        frag_cd acc[4][4] = {};
        for (int ks = 0; ks < 16; ++ks) {
            frag_ab bfr[4];
#pragma unroll
            for (int ct = 0; ct < 4; ++ct)
                bfr[ct] = *reinterpret_cast<const frag_ab*>(
                    cur + (ct * 16 + lr) * LDST + ks * 32 + q * 8);
#pragma unroll
            for (int mi = 0; mi < 4; ++mi) {
                frag_ab a = loadA(wave + mi * 8, ks);
#pragma unroll
                for (int ct = 0; ct < 4; ++ct)
                    acc[mi][ct] = __builtin_amdgcn_mfma_f32_16x16x32_bf16(
                        a, bfr[ct], acc[mi][ct], 0, 0, 0);
            }
        }
#pragma unroll
        for (int mi = 0; mi < 4; ++mi) {
            int row0 = (wave + mi * 8) * 16 + q * 4;
#pragma unroll
            for (int ct = 0; ct < 4; ++ct) {
                uint16_t* dp = dst + (ct * 16 + lr) * LDST + row0;
                float pz[4] = {0.f, 0.f, 0.f, 0.f};
                if (!first) {
                    ushort4 pv = *reinterpret_cast<const ushort4*>(dp);
                    pz[0] = bf2f(pv.x); pz[1] = bf2f(pv.y);
                    pz[2] = bf2f(pv.z); pz[3] = bf2f(pv.w);
                }
                ushort4 nv;
                float v0 = acc[mi][ct][0], v1 = acc[mi][ct][1];
                float v2 = acc[mi][ct][2], v3 = acc[mi][ct][3];
                if (!first) {
                    v0 = 2.f * v0 - pz[0]; v1 = 2.f * v1 - pz[1];
                    v2 = 2.f * v2 - pz[2]; v3 = 2.f * v3 - pz[3];
                }
                nv.x = f2bf(v0); nv.y = f2bf(v1); nv.z = f2bf(v2); nv.w = f2bf(v3);
                *reinterpret_cast<ushort4*>(dp) = nv;
            }
        }
    };

    auto epi = [&](const uint16_t* bA, const uint16_t* bB, frag_ab wfr) {
        const uint16_t* base = (q < 2) ? bA : bB;
        int finb = (q & 1) * 8;
#pragma unroll
        for (int mi = 0; mi < 4; ++mi) {
            int n = (wave + mi * 8) * 16 + lr;
#pragma unroll
            for (int bt = 0; bt < 4; ++bt) {
                const uint16_t* pp = base + (bt * 16 + finb) * LDST + n;
                frag_ab afr;
#pragma unroll
                for (int jj = 0; jj < 8; ++jj) afr[jj] = (short)pp[jj * LDST];
                accOut[mi][bt] = __builtin_amdgcn_mfma_f32_16x16x32_bf16(
                    afr, wfr, accOut[mi][bt], 0, 0, 0);
            }
        }
    };

    __syncthreads();
    app(z0, z1, true);
    __syncthreads();
    epi(z0, z1, wf[0]);
    __syncthreads();
    app(z1, z0, false);
    __syncthreads();
    app(z0, z1, false);
    __syncthreads();
    epi(z0, z1, wf[1]);
    __syncthreads();
    app(z1, z0, false);
    __syncthreads();
    epi(z0, z0, wf[2]);

    if (lr < 8) {
        float* ob = out + (size_t)blockIdx.x * BT1 * BN * FOUT;
#pragma unroll
        for (int mi = 0; mi < 4; ++mi) {
            int row0 = (wave + mi * 8) * 16 + q * 4;
#pragma unroll
            for (int bt = 0; bt < 4; ++bt) {
                float* op = ob + bt * (BN * FOUT) + row0 * FOUT + lr;
                op[0 * FOUT] = accOut[mi][bt][0] + bv;
                op[1 * FOUT] = accOut[mi][bt][1] + bv;
                op[2 * FOUT] = accOut[mi][bt][2] + bv;
                op[3 * FOUT] = accOut[mi][bt][3] + bv;
            }
        }
    }
}

extern "C" void kernel_launch(void* const* d_in, const int* in_sizes, int n_in,
                              void* d_out, int out_size, void* d_ws, size_t ws_size,
                              hipStream_t stream) {
    const float* x  = (const float*)d_in[0];   // [1024,512,16]
    const float* Lf = (const float*)d_in[1];   // [512,512]
    const float* W  = (const float*)d_in[2];   // [5,16,8]
    const float* bv = (const float*)d_in[3];   // [8]
    float* out = (float*)d_out;                // [1024,512,8]

    const size_t matB = (size_t)BN * BN * sizeof(uint16_t);   // 512 KiB

    if (ws_size >= 2 * matB) {
        // Primary path: swizzled Lb = bf16(L), Mb = bf16(2L^2 - I), BT=2 kernel.
        uint16_t* Lb = (uint16_t*)d_ws;
        uint16_t* Mb = Lb + (size_t)BN * BN;
        cvtL_swz<<<dim3(128), dim3(256), 0, stream>>>(Lf, Lb);
        m2comp<<<dim3(256), dim3(256), 0, stream>>>(Lf, Mb);
        cheb2_kernel<<<dim3(512), dim3(512), 0, stream>>>(x, Lb, Mb, W, bv, out);
    } else if (ws_size >= matB) {
        uint16_t* Lb = (uint16_t*)d_ws;
        cvtL_rm<<<dim3(1024), dim3(256), 0, stream>>>(Lf, Lb);
        cheb1_kernel<true><<<dim3(256), dim3(512), 0, stream>>>(x, Lf, Lb, W, bv, out);
    } else {
        cheb1_kernel<false><<<dim3(256), dim3(512), 0, stream>>>(x, Lf, nullptr, W, bv, out);
    }
}

// Round 5
// 177.739 us; speedup vs baseline: 1.1136x; 1.1136x over previous
//
#include <hip/hip_runtime.h>
#include <cstdint>
#include <cstddef>

// ManualChebConv via Chebyshev composition, v5: A-stream latency hiding.
//   M2 := T2(L) = 2L^2 - I  (precomputed bf16, split-precision MFMA)
//   Round 1: Z1 = L@Z0, Z2 = M2@Z0   (one fused K-pass, shared B-frags)
//   Round 2: S3 = 2L@Z2, S4 = 2M2@Z2
//   out = Z0@(W0-W4) + Z1@(W1-W3) + Z2@W2 + S3@W3 + S4@W4 + b
//
// v5 change (post-mortem of v4): 2-blocks/CU (BT=2) doubled occupancy but
// doubled A-traffic per MFMA and squeezed registers -> 319MB TCC traffic,
// regression. Reverting to v3 structure (BT=4, 256 blocks, 1 block/CU).
// v3's 86us is ~50% issue-idle: 8 x 1KB A-fragment loads per ks are L1-miss
// -> ~250cy L2 latency exposed per mi-group with only 2 waves/SIMD.
// Fix: 2-deep software pipeline - prefetch ks+1's A-fragments into registers
// before ks's 32 MFMAs (compiler emits counted vmcnt, loads stay in flight).

typedef __attribute__((ext_vector_type(8))) short  frag_ab;  // 8 bf16
typedef __attribute__((ext_vector_type(4))) float  frag_cd;  // 4 fp32

constexpr int BN    = 512;        // N
constexpr int FIN   = 16;
constexpr int FOUT  = 8;
constexpr int BT    = 4;          // batches per block
constexpr int NCOLS = BT * FIN;   // 64 combined cols
constexpr int LDST  = BN + 8;     // padded stride (bank-friendly, 16B aligned)
constexpr int ZBUF  = NCOLS * LDST;   // 33280 u16 = 66,560 B per buffer

__device__ __forceinline__ uint16_t f2bf(float f) {
    uint32_t u = __builtin_bit_cast(uint32_t, f);
    u += 0x7FFFu + ((u >> 16) & 1u);          // round-to-nearest-even
    return (uint16_t)(u >> 16);
}
__device__ __forceinline__ float bf2f(uint16_t h) {
    uint32_t u = ((uint32_t)h) << 16;
    return __builtin_bit_cast(float, u);
}

// Fragment-order ("swizzled") index for an A-matrix element (row, k):
// fragment f = (row/16)*16 + (k/32); lane = ((k>>3)&3)*16 + (row&15); elem j = k&7.
__device__ __forceinline__ size_t aswz(int row, int k) {
    return ((size_t)((row >> 4) * 16 + (k >> 5)) * 64
            + ((k >> 3) & 3) * 16 + (row & 15)) * 8 + (k & 7);
}

// Row-major bf16 conversion (fallback path only)
__global__ void cvtL_rm(const float* __restrict__ Lf, uint16_t* __restrict__ Lb) {
    int i = blockIdx.x * 256 + threadIdx.x;   // 1024 x 256 = 262144
    Lb[i] = f2bf(Lf[i]);
}

// Swizzled bf16 conversion: thread t produces one lane-fragment (8 contiguous
// bf16 at output t*8). Output fully coalesced.
__global__ __launch_bounds__(256)
void cvtL_swz(const float* __restrict__ Lf, uint16_t* __restrict__ Lb) {
    int t = blockIdx.x * 256 + threadIdx.x;   // 128 x 256 = 32768
    int f = t >> 6, lane = t & 63;
    int mt = f >> 4, ks = f & 15;
    int row = mt * 16 + (lane & 15);
    int k0  = ks * 32 + (lane >> 4) * 8;
    const float4* p = reinterpret_cast<const float4*>(Lf + (size_t)row * BN + k0);
    float4 u0 = p[0], u1 = p[1];
    frag_ab o;
    o[0] = (short)f2bf(u0.x); o[1] = (short)f2bf(u0.y);
    o[2] = (short)f2bf(u0.z); o[3] = (short)f2bf(u0.w);
    o[4] = (short)f2bf(u1.x); o[5] = (short)f2bf(u1.y);
    o[6] = (short)f2bf(u1.z); o[7] = (short)f2bf(u1.w);
    *reinterpret_cast<frag_ab*>(Lb + (size_t)t * 8) = o;
}

// M2 = 2*L@L - I in bf16 (swizzled output), from fp32 L. Split-bf16 (hi/lo)
// MFMA: error ~ one bf16 rounding. L symmetric -> B[k][j] = L[j][k].
__global__ __launch_bounds__(256)
void m2comp(const float* __restrict__ Lf, uint16_t* __restrict__ Mb) {
    const int tid = threadIdx.x;
    const int wv = tid >> 6, lane = tid & 63, lr = lane & 15, q = lane >> 4;
    const int i0 = (blockIdx.x >> 4) * 32 + (wv >> 1) * 16;
    const int j0 = (blockIdx.x & 15) * 32 + (wv & 1) * 16;
    frag_cd acc = {0.f, 0.f, 0.f, 0.f};
    const float* arow = Lf + (size_t)(i0 + lr) * BN;   // A[m][k] = L[i0+m][k]
    const float* brow = Lf + (size_t)(j0 + lr) * BN;   // B[k][n] = L[j0+n][k]
    for (int ks = 0; ks < 16; ++ks) {
        const int kb = ks * 32 + q * 8;
        const float4* ap = reinterpret_cast<const float4*>(arow + kb);
        const float4* bp = reinterpret_cast<const float4*>(brow + kb);
        float4 a0 = ap[0], a1 = ap[1], b0 = bp[0], b1 = bp[1];
        float av[8]  = {a0.x, a0.y, a0.z, a0.w, a1.x, a1.y, a1.z, a1.w};
        float bvv[8] = {b0.x, b0.y, b0.z, b0.w, b1.x, b1.y, b1.z, b1.w};
        frag_ab ah, al, bh, bl;
#pragma unroll
        for (int j = 0; j < 8; ++j) {
            uint16_t h = f2bf(av[j]);
            ah[j] = (short)h;
            al[j] = (short)f2bf(av[j] - bf2f(h));
            uint16_t g = f2bf(bvv[j]);
            bh[j] = (short)g;
            bl[j] = (short)f2bf(bvv[j] - bf2f(g));
        }
        acc = __builtin_amdgcn_mfma_f32_16x16x32_bf16(ah, bh, acc, 0, 0, 0);
        acc = __builtin_amdgcn_mfma_f32_16x16x32_bf16(ah, bl, acc, 0, 0, 0);
        acc = __builtin_amdgcn_mfma_f32_16x16x32_bf16(al, bh, acc, 0, 0, 0);
    }
#pragma unroll
    for (int r = 0; r < 4; ++r) {
        int i = i0 + q * 4 + r, j = j0 + lr;
        float v = 2.f * acc[r] - ((i == j) ? 1.f : 0.f);
        Mb[aswz(i, j)] = f2bf(v);
    }
}

__global__ __launch_bounds__(512, 2)
void cheb2_kernel(const float* __restrict__ x, const uint16_t* __restrict__ Lb,
                  const uint16_t* __restrict__ Mb, const float* __restrict__ W,
                  const float* __restrict__ bvec, float* __restrict__ out) {
    __shared__ uint16_t lds[2 * ZBUF];        // 133,120 B
    uint16_t* z0 = lds;
    uint16_t* z1 = lds + ZBUF;

    const int tid  = threadIdx.x;
    const int wave = tid >> 6;                // 0..7
    const int lane = tid & 63;
    const int lr   = lane & 15;
    const int q    = lane >> 4;

    // ---------------- stage x -> Z0^T (bf16) in z0 ----------------
    const float4* x4 = reinterpret_cast<const float4*>(x + (size_t)blockIdx.x * (BT * BN * FIN));
    for (int s = 0; s < 2; ++s) {
        int a   = tid + s * 512;
        int f0g = a & 3;
        int n8  = (a >> 2) & 63;
        int bl  = a >> 8;
        int jb  = bl * 2048 + n8 * 32 + f0g;
        float4 v[8];
#pragma unroll
        for (int r = 0; r < 8; ++r) v[r] = x4[jb + r * 4];
        int cb = bl * 16 + f0g * 4;
        int nb = n8 * 8;
#pragma unroll
        for (int w = 0; w < 4; ++w) {
            frag_ab pk;
#pragma unroll
            for (int r = 0; r < 8; ++r)
                pk[r] = (short)f2bf(reinterpret_cast<const float*>(&v[r])[w]);
            *reinterpret_cast<frag_ab*>(&z0[(cb + w) * LDST + nb]) = pk;
        }
    }

    // ---------------- combined W pair B-fragments + bias ----------------
    // Effective weights: E0=W0-W4, E1=W1-W3, E2=W2, E3=W3, E4=W4, E5=0.
    frag_ab wf[3];
#pragma unroll
    for (int p = 0; p < 3; ++p) {
        frag_ab t;
#pragma unroll
        for (int jj = 0; jj < 8; ++jj) {
            int k   = q * 8 + jj;
            int ki  = p * 2 + (k >> 4);
            int fin = k & 15;
            float val = 0.0f;
            if (lr < 8) {
                int idx = fin * FOUT + lr;
                if      (ki == 0) val = W[idx] - W[4 * (FIN * FOUT) + idx];
                else if (ki == 1) val = W[1 * (FIN * FOUT) + idx] - W[3 * (FIN * FOUT) + idx];
                else if (ki < 5)  val = W[ki * (FIN * FOUT) + idx];
            }
            t[jj] = (short)f2bf(val);
        }
        wf[p] = t;
    }
    const float bv = (lr < 8) ? bvec[lr] : 0.0f;

    frag_cd accOut[4][4] = {};                // [mtIdx][bt] out tiles (fp32)

    // A-fragment from swizzled layout: dense 1KB burst, lane*16B contiguous.
    auto ldfrag = [&](const uint16_t* M, int mt, int ks) -> frag_ab {
        return *reinterpret_cast<const frag_ab*>(
            M + ((size_t)(mt * 16 + ks) * 64 + lane) * 8);
    };

    frag_cd acc1[4][4];                       // L  @ cur
    frag_cd acc2[4][4];                       // M2 @ cur

    // One fused K-pass with 2-deep A-fragment software pipeline:
    // while MFMAs consume set X (ks), set Y (ks+1) is in flight.
    auto round = [&](const uint16_t* cur) {
#pragma unroll
        for (int mi = 0; mi < 4; ++mi)
#pragma unroll
            for (int ct = 0; ct < 4; ++ct) {
                acc1[mi][ct] = (frag_cd){0.f, 0.f, 0.f, 0.f};
                acc2[mi][ct] = (frag_cd){0.f, 0.f, 0.f, 0.f};
            }
        frag_ab aA[4], mA[4], aB[4], mB[4];   // double-buffered A-frags (64 VGPR)
#pragma unroll
        for (int mi = 0; mi < 4; ++mi) {
            aA[mi] = ldfrag(Lb, wave + mi * 8, 0);
            mA[mi] = ldfrag(Mb, wave + mi * 8, 0);
        }
        for (int ks = 0; ks < 16; ks += 2) {
            // issue ks+1 loads (land while ks computes)
#pragma unroll
            for (int mi = 0; mi < 4; ++mi) {
                aB[mi] = ldfrag(Lb, wave + mi * 8, ks + 1);
                mB[mi] = ldfrag(Mb, wave + mi * 8, ks + 1);
            }
            {   // compute ks with set A
                frag_ab bfr[4];
#pragma unroll
                for (int ct = 0; ct < 4; ++ct)
                    bfr[ct] = *reinterpret_cast<const frag_ab*>(
                        cur + (ct * 16 + lr) * LDST + ks * 32 + q * 8);
#pragma unroll
                for (int mi = 0; mi < 4; ++mi) {
#pragma unroll
                    for (int ct = 0; ct < 4; ++ct)
                        acc1[mi][ct] = __builtin_amdgcn_mfma_f32_16x16x32_bf16(
                            aA[mi], bfr[ct], acc1[mi][ct], 0, 0, 0);
#pragma unroll
                    for (int ct = 0; ct < 4; ++ct)
                        acc2[mi][ct] = __builtin_amdgcn_mfma_f32_16x16x32_bf16(
                            mA[mi], bfr[ct], acc2[mi][ct], 0, 0, 0);
                }
            }
            // issue ks+2 loads (land while ks+1 computes)
            if (ks + 2 < 16) {
#pragma unroll
                for (int mi = 0; mi < 4; ++mi) {
                    aA[mi] = ldfrag(Lb, wave + mi * 8, ks + 2);
                    mA[mi] = ldfrag(Mb, wave + mi * 8, ks + 2);
                }
            }
            {   // compute ks+1 with set B
                frag_ab bfr[4];
#pragma unroll
                for (int ct = 0; ct < 4; ++ct)
                    bfr[ct] = *reinterpret_cast<const frag_ab*>(
                        cur + (ct * 16 + lr) * LDST + (ks + 1) * 32 + q * 8);
#pragma unroll
                for (int mi = 0; mi < 4; ++mi) {
#pragma unroll
                    for (int ct = 0; ct < 4; ++ct)
                        acc1[mi][ct] = __builtin_amdgcn_mfma_f32_16x16x32_bf16(
                            aB[mi], bfr[ct], acc1[mi][ct], 0, 0, 0);
#pragma unroll
                    for (int ct = 0; ct < 4; ++ct)
                        acc2[mi][ct] = __builtin_amdgcn_mfma_f32_16x16x32_bf16(
                            mB[mi], bfr[ct], acc2[mi][ct], 0, 0, 0);
                }
            }
        }
    };

    // Plain writeback: dst <- bf16(scale * acc)  (no RMW anywhere)
    auto wb = [&](frag_cd (&acc)[4][4], uint16_t* dst, float scale) {
#pragma unroll
        for (int mi = 0; mi < 4; ++mi) {
            int row0 = (wave + mi * 8) * 16 + q * 4;
#pragma unroll
            for (int ct = 0; ct < 4; ++ct) {
                uint16_t* dp = dst + (ct * 16 + lr) * LDST + row0;
                ushort4 nv;
                nv.x = f2bf(scale * acc[mi][ct][0]);
                nv.y = f2bf(scale * acc[mi][ct][1]);
                nv.z = f2bf(scale * acc[mi][ct][2]);
                nv.w = f2bf(scale * acc[mi][ct][3]);
                *reinterpret_cast<ushort4*>(dp) = nv;
            }
        }
    };

    // Paired epilogue: accOut += [bufA | bufB](A-layout) @ wfr
    auto epi = [&](const uint16_t* bA, const uint16_t* bB, frag_ab wfr) {
        const uint16_t* base = (q < 2) ? bA : bB;
        int finb = (q & 1) * 8;
#pragma unroll
        for (int mi = 0; mi < 4; ++mi) {
            int n = (wave + mi * 8) * 16 + lr;
#pragma unroll
            for (int bt = 0; bt < 4; ++bt) {
                const uint16_t* pp = base + (bt * 16 + finb) * LDST + n;
                frag_ab afr;
#pragma unroll
                for (int jj = 0; jj < 8; ++jj) afr[jj] = (short)pp[jj * LDST];
                accOut[mi][bt] = __builtin_amdgcn_mfma_f32_16x16x32_bf16(
                    afr, wfr, accOut[mi][bt], 0, 0, 0);
            }
        }
    };

    __syncthreads();                  // staging visible
    round(z0);                        // acc1 = Z1 = L@Z0, acc2 = Z2 = M2@Z0
    wb(acc1, z1, 1.f);                // z1 <- Z1 (z1 unread so far: no barrier needed)
    __syncthreads();                  // Z1 visible
    epi(z0, z1, wf[0]);               // accOut += Z0@(W0-W4) + Z1@(W1-W3)
    __syncthreads();                  // all z0 reads (K-pass + epi0) done
    wb(acc2, z0, 1.f);                // z0 <- Z2 (in-place over Z0)
    __syncthreads();                  // Z2 visible
    round(z0);                        // acc1 = L@Z2, acc2 = M2@Z2
    wb(acc1, z1, 2.f);                // z1 <- S3 = 2L@Z2 (z1 dead since epi0 barrier)
    __syncthreads();                  // S3 visible, K-pass z0 reads done
    epi(z0, z1, wf[1]);               // accOut += Z2@W2 + S3@W3
    __syncthreads();                  // epi1's z0 reads done (z1 also dead after this)
    wb(acc2, z0, 2.f);                // z0 <- S4 = 2M2@Z2
    __syncthreads();                  // S4 visible
    epi(z0, z0, wf[2]);               // accOut += S4@W4 (second-half weights zero)

    // ---------------- store via LDS (dense float4 bursts) ----------------
    // z1 is dead (last read in epi1, >=2 barriers ago). Stage [bt][n][fo] fp32
    // (65,536 B <= ZBUF's 66,560 B), then 8 coalesced float4 stores/thread.
    float* fbuf = reinterpret_cast<float*>(z1);
    if (lr < 8) {
#pragma unroll
        for (int mi = 0; mi < 4; ++mi) {
            int n0 = (wave + mi * 8) * 16 + q * 4;
#pragma unroll
            for (int bt = 0; bt < 4; ++bt) {
#pragma unroll
                for (int r = 0; r < 4; ++r)
                    fbuf[(bt * BN + n0 + r) * FOUT + lr] = accOut[mi][bt][r] + bv;
            }
        }
    }
    __syncthreads();
    {
        const float4* fb4 = reinterpret_cast<const float4*>(fbuf);
        float4* o4 = reinterpret_cast<float4*>(out + (size_t)blockIdx.x * (BT * BN * FOUT));
#pragma unroll
        for (int i = 0; i < 8; ++i)
            o4[i * 512 + tid] = fb4[i * 512 + tid];
    }
}

// ---------------- v1 fallback (4-app recurrence), used if ws too small ----------------
template <bool LBF16>
__global__ __launch_bounds__(512, 2)
void cheb1_kernel(const float* __restrict__ x, const float* __restrict__ Lf,
                  const uint16_t* __restrict__ Lb, const float* __restrict__ W,
                  const float* __restrict__ bvec, float* __restrict__ out) {
    __shared__ uint16_t lds[2 * ZBUF];
    uint16_t* z0 = lds;
    uint16_t* z1 = lds + ZBUF;

    const int tid  = threadIdx.x;
    const int wave = tid >> 6;
    const int lane = tid & 63;
    const int lr   = lane & 15;
    const int q    = lane >> 4;

    const float4* x4 = reinterpret_cast<const float4*>(x + (size_t)blockIdx.x * (BT * BN * FIN));
    for (int s = 0; s < 2; ++s) {
        int a   = tid + s * 512;
        int f0g = a & 3;
        int n8  = (a >> 2) & 63;
        int bl  = a >> 8;
        int jb  = bl * 2048 + n8 * 32 + f0g;
        float4 v[8];
#pragma unroll
        for (int r = 0; r < 8; ++r) v[r] = x4[jb + r * 4];
        int cb = bl * 16 + f0g * 4;
        int nb = n8 * 8;
#pragma unroll
        for (int w = 0; w < 4; ++w) {
            frag_ab pk;
#pragma unroll
            for (int r = 0; r < 8; ++r)
                pk[r] = (short)f2bf(reinterpret_cast<const float*>(&v[r])[w]);
            *reinterpret_cast<frag_ab*>(&z0[(cb + w) * LDST + nb]) = pk;
        }
    }

    frag_ab wf[3];
#pragma unroll
    for (int p = 0; p < 3; ++p) {
        frag_ab t;
#pragma unroll
        for (int jj = 0; jj < 8; ++jj) {
            int k   = q * 8 + jj;
            int ki  = p * 2 + (k >> 4);
            int fin = k & 15;
            float val = (lr < 8 && ki < 5) ? W[ki * (FIN * FOUT) + fin * FOUT + lr] : 0.0f;
            t[jj] = (short)f2bf(val);
        }
        wf[p] = t;
    }
    const float bv = (lr < 8) ? bvec[lr] : 0.0f;

    frag_cd accOut[4][4] = {};

    auto loadA = [&](int mt, int ks) -> frag_ab {
        int row = mt * 16 + lr;
        int kb  = ks * 32 + q * 8;
        if constexpr (LBF16) {
            return *reinterpret_cast<const frag_ab*>(Lb + row * BN + kb);
        } else {
            const float4* p  = reinterpret_cast<const float4*>(Lf + row * BN + kb);
            float4 u0 = p[0], u1 = p[1];
            frag_ab t;
            t[0] = (short)f2bf(u0.x); t[1] = (short)f2bf(u0.y);
            t[2] = (short)f2bf(u0.z); t[3] = (short)f2bf(u0.w);
            t[4] = (short)f2bf(u1.x); t[5] = (short)f2bf(u1.y);
            t[6] = (short)f2bf(u1.z); t[7] = (short)f2bf(u1.w);
            return t;
        }
    };

    auto app = [&](const uint16_t* cur, uint16_t* dst, bool first) {
        frag_cd acc[4][4] = {};
        for (int ks = 0; ks < 16; ++ks) {
            frag_ab bfr[4];
#pragma unroll
            for (int ct = 0; ct < 4; ++ct)
                bfr[ct] = *reinterpret_cast<const frag_ab*>(
                    cur + (ct * 16 + lr) * LDST + ks * 32 + q * 8);
#pragma unroll
            for (int mi = 0; mi < 4; ++mi) {
                frag_ab a = loadA(wave + mi * 8, ks);
#pragma unroll
                for (int ct = 0; ct < 4; ++ct)
                    acc[mi][ct] = __builtin_amdgcn_mfma_f32_16x16x32_bf16(
                        a, bfr[ct], acc[mi][ct], 0, 0, 0);
            }
        }
#pragma unroll
        for (int mi = 0; mi < 4; ++mi) {
            int row0 = (wave + mi * 8) * 16 + q * 4;
#pragma unroll
            for (int ct = 0; ct < 4; ++ct) {
                uint16_t* dp = dst + (ct * 16 + lr) * LDST + row0;
                float pz[4] = {0.f, 0.f, 0.f, 0.f};
                if (!first) {
                    ushort4 pv = *reinterpret_cast<const ushort4*>(dp);
                    pz[0] = bf2f(pv.x); pz[1] = bf2f(pv.y);
                    pz[2] = bf2f(pv.z); pz[3] = bf2f(pv.w);
                }
                ushort4 nv;
                float v0 = acc[mi][ct][0], v1 = acc[mi][ct][1];
                float v2 = acc[mi][ct][2], v3 = acc[mi][ct][3];
                if (!first) {
                    v0 = 2.f * v0 - pz[0]; v1 = 2.f * v1 - pz[1];
                    v2 = 2.f * v2 - pz[2]; v3 = 2.f * v3 - pz[3];
                }
                nv.x = f2bf(v0); nv.y = f2bf(v1); nv.z = f2bf(v2); nv.w = f2bf(v3);
                *reinterpret_cast<ushort4*>(dp) = nv;
            }
        }
    };

    auto epi = [&](const uint16_t* bA, const uint16_t* bB, frag_ab wfr) {
        const uint16_t* base = (q < 2) ? bA : bB;
        int finb = (q & 1) * 8;
#pragma unroll
        for (int mi = 0; mi < 4; ++mi) {
            int n = (wave + mi * 8) * 16 + lr;
#pragma unroll
            for (int bt = 0; bt < 4; ++bt) {
                const uint16_t* pp = base + (bt * 16 + finb) * LDST + n;
                frag_ab afr;
#pragma unroll
                for (int jj = 0; jj < 8; ++jj) afr[jj] = (short)pp[jj * LDST];
                accOut[mi][bt] = __builtin_amdgcn_mfma_f32_16x16x32_bf16(
                    afr, wfr, accOut[mi][bt], 0, 0, 0);
            }
        }
    };

    __syncthreads();
    app(z0, z1, true);
    __syncthreads();
    epi(z0, z1, wf[0]);
    __syncthreads();
    app(z1, z0, false);
    __syncthreads();
    app(z0, z1, false);
    __syncthreads();
    epi(z0, z1, wf[1]);
    __syncthreads();
    app(z1, z0, false);
    __syncthreads();
    epi(z0, z0, wf[2]);

    if (lr < 8) {
        float* ob = out + (size_t)blockIdx.x * BT * BN * FOUT;
#pragma unroll
        for (int mi = 0; mi < 4; ++mi) {
            int row0 = (wave + mi * 8) * 16 + q * 4;
#pragma unroll
            for (int bt = 0; bt < 4; ++bt) {
                float* op = ob + bt * (BN * FOUT) + row0 * FOUT + lr;
                op[0 * FOUT] = accOut[mi][bt][0] + bv;
                op[1 * FOUT] = accOut[mi][bt][1] + bv;
                op[2 * FOUT] = accOut[mi][bt][2] + bv;
                op[3 * FOUT] = accOut[mi][bt][3] + bv;
            }
        }
    }
}

extern "C" void kernel_launch(void* const* d_in, const int* in_sizes, int n_in,
                              void* d_out, int out_size, void* d_ws, size_t ws_size,
                              hipStream_t stream) {
    const float* x  = (const float*)d_in[0];   // [1024,512,16]
    const float* Lf = (const float*)d_in[1];   // [512,512]
    const float* W  = (const float*)d_in[2];   // [5,16,8]
    const float* bv = (const float*)d_in[3];   // [8]
    float* out = (float*)d_out;                // [1024,512,8]

    const size_t matB = (size_t)BN * BN * sizeof(uint16_t);   // 512 KiB

    if (ws_size >= 2 * matB) {
        // Primary path: swizzled Lb = bf16(L), Mb = bf16(2L^2 - I), BT=4 kernel.
        uint16_t* Lb = (uint16_t*)d_ws;
        uint16_t* Mb = Lb + (size_t)BN * BN;
        cvtL_swz<<<dim3(128), dim3(256), 0, stream>>>(Lf, Lb);
        m2comp<<<dim3(256), dim3(256), 0, stream>>>(Lf, Mb);
        cheb2_kernel<<<dim3(256), dim3(512), 0, stream>>>(x, Lb, Mb, W, bv, out);
    } else if (ws_size >= matB) {
        uint16_t* Lb = (uint16_t*)d_ws;
        cvtL_rm<<<dim3(1024), dim3(256), 0, stream>>>(Lf, Lb);
        cheb1_kernel<true><<<dim3(256), dim3(512), 0, stream>>>(x, Lf, Lb, W, bv, out);
    } else {
        cheb1_kernel<false><<<dim3(256), dim3(512), 0, stream>>>(x, Lf, nullptr, W, bv, out);
    }
}

// Round 6
// 172.225 us; speedup vs baseline: 1.1492x; 1.0320x over previous
//
#include <hip/hip_runtime.h>
#include <cstdint>
#include <cstddef>

// ManualChebConv via Chebyshev composition, v6: 4 waves/SIMD via 1024-thr blocks.
//   M2 := T2(L) = 2L^2 - I  (precomputed bf16, split-precision MFMA)
//   Round 1: Z1 = L@Z0 (pass), Z2 = M2@Z0 (pass)
//   Round 2: S3 = 2L@Z2, S4 = 2M2@Z2
//   out = Z0@(W0-W4) + Z1@(W1-W3) + Z2@W2 + S3@W3 + S4@W4 + b
//
// v6 change (post-mortems v3-v5): v3 (86us) is idle-bound at 2 waves/SIMD;
// v4 (more blocks/CU) exploded traffic; v5 (reg prefetch) spilled. Fix that
// attacks latency WITHOUT extra traffic or registers: 256 blocks x 1024 thr
// (16 waves -> 4 waves/SIMD, 1 block/CU, same A-stream). Per-wave work halves
// (2 M-tiles), and the L/M2 passes run sequentially so only one acc[2][4] is
// live -> fits the 128-reg/wave budget of 4 waves/SIMD without spill.

typedef __attribute__((ext_vector_type(8))) short  frag_ab;  // 8 bf16
typedef __attribute__((ext_vector_type(4))) float  frag_cd;  // 4 fp32

constexpr int BN    = 512;        // N
constexpr int FIN   = 16;
constexpr int FOUT  = 8;
constexpr int BT    = 4;          // batches per block
constexpr int NCOLS = BT * FIN;   // 64 combined cols
constexpr int LDST  = BN + 8;     // padded stride (bank-friendly, 16B aligned)
constexpr int ZBUF  = NCOLS * LDST;   // 33280 u16 = 66,560 B per buffer

__device__ __forceinline__ uint16_t f2bf(float f) {
    uint32_t u = __builtin_bit_cast(uint32_t, f);
    u += 0x7FFFu + ((u >> 16) & 1u);          // round-to-nearest-even
    return (uint16_t)(u >> 16);
}
__device__ __forceinline__ float bf2f(uint16_t h) {
    uint32_t u = ((uint32_t)h) << 16;
    return __builtin_bit_cast(float, u);
}

// Fragment-order ("swizzled") index for an A-matrix element (row, k):
// fragment f = (row/16)*16 + (k/32); lane = ((k>>3)&3)*16 + (row&15); elem j = k&7.
__device__ __forceinline__ size_t aswz(int row, int k) {
    return ((size_t)((row >> 4) * 16 + (k >> 5)) * 64
            + ((k >> 3) & 3) * 16 + (row & 15)) * 8 + (k & 7);
}

// Row-major bf16 conversion (fallback path only)
__global__ void cvtL_rm(const float* __restrict__ Lf, uint16_t* __restrict__ Lb) {
    int i = blockIdx.x * 256 + threadIdx.x;   // 1024 x 256 = 262144
    Lb[i] = f2bf(Lf[i]);
}

// Swizzled bf16 conversion: thread t produces one lane-fragment (8 contiguous
// bf16 at output t*8). Output fully coalesced.
__global__ __launch_bounds__(256)
void cvtL_swz(const float* __restrict__ Lf, uint16_t* __restrict__ Lb) {
    int t = blockIdx.x * 256 + threadIdx.x;   // 128 x 256 = 32768
    int f = t >> 6, lane = t & 63;
    int mt = f >> 4, ks = f & 15;
    int row = mt * 16 + (lane & 15);
    int k0  = ks * 32 + (lane >> 4) * 8;
    const float4* p = reinterpret_cast<const float4*>(Lf + (size_t)row * BN + k0);
    float4 u0 = p[0], u1 = p[1];
    frag_ab o;
    o[0] = (short)f2bf(u0.x); o[1] = (short)f2bf(u0.y);
    o[2] = (short)f2bf(u0.z); o[3] = (short)f2bf(u0.w);
    o[4] = (short)f2bf(u1.x); o[5] = (short)f2bf(u1.y);
    o[6] = (short)f2bf(u1.z); o[7] = (short)f2bf(u1.w);
    *reinterpret_cast<frag_ab*>(Lb + (size_t)t * 8) = o;
}

// M2 = 2*L@L - I in bf16 (swizzled output), from fp32 L. Split-bf16 (hi/lo)
// MFMA: error ~ one bf16 rounding. L symmetric -> B[k][j] = L[j][k].
__global__ __launch_bounds__(256)
void m2comp(const float* __restrict__ Lf, uint16_t* __restrict__ Mb) {
    const int tid = threadIdx.x;
    const int wv = tid >> 6, lane = tid & 63, lr = lane & 15, q = lane >> 4;
    const int i0 = (blockIdx.x >> 4) * 32 + (wv >> 1) * 16;
    const int j0 = (blockIdx.x & 15) * 32 + (wv & 1) * 16;
    frag_cd acc = {0.f, 0.f, 0.f, 0.f};
    const float* arow = Lf + (size_t)(i0 + lr) * BN;   // A[m][k] = L[i0+m][k]
    const float* brow = Lf + (size_t)(j0 + lr) * BN;   // B[k][n] = L[j0+n][k]
    for (int ks = 0; ks < 16; ++ks) {
        const int kb = ks * 32 + q * 8;
        const float4* ap = reinterpret_cast<const float4*>(arow + kb);
        const float4* bp = reinterpret_cast<const float4*>(brow + kb);
        float4 a0 = ap[0], a1 = ap[1], b0 = bp[0], b1 = bp[1];
        float av[8]  = {a0.x, a0.y, a0.z, a0.w, a1.x, a1.y, a1.z, a1.w};
        float bvv[8] = {b0.x, b0.y, b0.z, b0.w, b1.x, b1.y, b1.z, b1.w};
        frag_ab ah, al, bh, bl;
#pragma unroll
        for (int j = 0; j < 8; ++j) {
            uint16_t h = f2bf(av[j]);
            ah[j] = (short)h;
            al[j] = (short)f2bf(av[j] - bf2f(h));
            uint16_t g = f2bf(bvv[j]);
            bh[j] = (short)g;
            bl[j] = (short)f2bf(bvv[j] - bf2f(g));
        }
        acc = __builtin_amdgcn_mfma_f32_16x16x32_bf16(ah, bh, acc, 0, 0, 0);
        acc = __builtin_amdgcn_mfma_f32_16x16x32_bf16(ah, bl, acc, 0, 0, 0);
        acc = __builtin_amdgcn_mfma_f32_16x16x32_bf16(al, bh, acc, 0, 0, 0);
    }
#pragma unroll
    for (int r = 0; r < 4; ++r) {
        int i = i0 + q * 4 + r, j = j0 + lr;
        float v = 2.f * acc[r] - ((i == j) ? 1.f : 0.f);
        Mb[aswz(i, j)] = f2bf(v);
    }
}

__global__ __launch_bounds__(1024, 4)
void cheb2_kernel(const float* __restrict__ x, const uint16_t* __restrict__ Lb,
                  const uint16_t* __restrict__ Mb, const float* __restrict__ W,
                  const float* __restrict__ bvec, float* __restrict__ out) {
    __shared__ uint16_t lds[2 * ZBUF];        // 133,120 B -> 1 block/CU, 16 waves
    uint16_t* z0 = lds;
    uint16_t* z1 = lds + ZBUF;

    const int tid  = threadIdx.x;
    const int wave = tid >> 6;                // 0..15
    const int lane = tid & 63;
    const int lr   = lane & 15;
    const int q    = lane >> 4;

    // ---------------- stage x -> Z0^T (bf16) in z0 ----------------
    // 1024 assignments, one per thread: (bl, f-chunk of 4, n-octet).
    const float4* x4 = reinterpret_cast<const float4*>(x + (size_t)blockIdx.x * (BT * BN * FIN));
    {
        int a   = tid;
        int f0g = a & 3;
        int n8  = (a >> 2) & 63;
        int bl  = a >> 8;                     // 0..3
        int jb  = bl * 2048 + n8 * 32 + f0g;
        float4 v[8];
#pragma unroll
        for (int r = 0; r < 8; ++r) v[r] = x4[jb + r * 4];
        int cb = bl * 16 + f0g * 4;
        int nb = n8 * 8;
#pragma unroll
        for (int w = 0; w < 4; ++w) {
            frag_ab pk;
#pragma unroll
            for (int r = 0; r < 8; ++r)
                pk[r] = (short)f2bf(reinterpret_cast<const float*>(&v[r])[w]);
            *reinterpret_cast<frag_ab*>(&z0[(cb + w) * LDST + nb]) = pk;
        }
    }

    // ---------------- combined W pair B-fragments + bias ----------------
    // Effective weights: E0=W0-W4, E1=W1-W3, E2=W2, E3=W3, E4=W4, E5=0.
    frag_ab wf[3];
#pragma unroll
    for (int p = 0; p < 3; ++p) {
        frag_ab t;
#pragma unroll
        for (int jj = 0; jj < 8; ++jj) {
            int k   = q * 8 + jj;
            int ki  = p * 2 + (k >> 4);
            int fin = k & 15;
            float val = 0.0f;
            if (lr < 8) {
                int idx = fin * FOUT + lr;
                if      (ki == 0) val = W[idx] - W[4 * (FIN * FOUT) + idx];
                else if (ki == 1) val = W[1 * (FIN * FOUT) + idx] - W[3 * (FIN * FOUT) + idx];
                else if (ki < 5)  val = W[ki * (FIN * FOUT) + idx];
            }
            t[jj] = (short)f2bf(val);
        }
        wf[p] = t;
    }
    const float bv = (lr < 8) ? bvec[lr] : 0.0f;

    frag_cd accOut[2][BT] = {};               // [mi][bt] out tiles (fp32)
    frag_cd acc[2][BT];                       // single-pass accumulator

    // One K-pass: acc = Amat @ cur. Each wave owns mt = wave, wave+16.
    // A pre-swizzled: dense 1KB bursts, lane*16B contiguous.
    auto pass = [&](const uint16_t* Amat, const uint16_t* cur) {
#pragma unroll
        for (int mi = 0; mi < 2; ++mi)
#pragma unroll
            for (int ct = 0; ct < BT; ++ct)
                acc[mi][ct] = (frag_cd){0.f, 0.f, 0.f, 0.f};
        for (int ks = 0; ks < 16; ++ks) {
            frag_ab bfr[BT];
#pragma unroll
            for (int ct = 0; ct < BT; ++ct)
                bfr[ct] = *reinterpret_cast<const frag_ab*>(
                    cur + (ct * 16 + lr) * LDST + ks * 32 + q * 8);
#pragma unroll
            for (int mi = 0; mi < 2; ++mi) {
                frag_ab a = *reinterpret_cast<const frag_ab*>(
                    Amat + ((size_t)((wave + mi * 16) * 16 + ks) * 64 + lane) * 8);
#pragma unroll
                for (int ct = 0; ct < BT; ++ct)
                    acc[mi][ct] = __builtin_amdgcn_mfma_f32_16x16x32_bf16(
                        a, bfr[ct], acc[mi][ct], 0, 0, 0);
            }
        }
    };

    // Plain writeback: dst <- bf16(scale * acc)  (no RMW anywhere)
    auto wb = [&](uint16_t* dst, float scale) {
#pragma unroll
        for (int mi = 0; mi < 2; ++mi) {
            int row0 = (wave + mi * 16) * 16 + q * 4;
#pragma unroll
            for (int ct = 0; ct < BT; ++ct) {
                uint16_t* dp = dst + (ct * 16 + lr) * LDST + row0;
                ushort4 nv;
                nv.x = f2bf(scale * acc[mi][ct][0]);
                nv.y = f2bf(scale * acc[mi][ct][1]);
                nv.z = f2bf(scale * acc[mi][ct][2]);
                nv.w = f2bf(scale * acc[mi][ct][3]);
                *reinterpret_cast<ushort4*>(dp) = nv;
            }
        }
    };

    // Paired epilogue: accOut += [bufA | bufB](A-layout) @ wfr
    auto epi = [&](const uint16_t* bA, const uint16_t* bB, frag_ab wfr) {
        const uint16_t* base = (q < 2) ? bA : bB;
        int finb = (q & 1) * 8;
#pragma unroll
        for (int mi = 0; mi < 2; ++mi) {
            int n = (wave + mi * 16) * 16 + lr;
#pragma unroll
            for (int bt = 0; bt < BT; ++bt) {
                const uint16_t* pp = base + (bt * 16 + finb) * LDST + n;
                frag_ab afr;
#pragma unroll
                for (int jj = 0; jj < 8; ++jj) afr[jj] = (short)pp[jj * LDST];
                accOut[mi][bt] = __builtin_amdgcn_mfma_f32_16x16x32_bf16(
                    afr, wfr, accOut[mi][bt], 0, 0, 0);
            }
        }
    };

    __syncthreads();                  // B1: z0 (Z0) visible
    pass(Lb, z0);                     // acc = Z1 = L@Z0
    wb(z1, 1.f);                      // z1 <- Z1 (z1 never read yet: safe)
    __syncthreads();                  // B2: Z1 visible
    epi(z0, z1, wf[0]);               // accOut += Z0@(W0-W4) + Z1@(W1-W3)
    pass(Mb, z0);                     // acc = Z2 = M2@Z0 (z0 read-only)
    __syncthreads();                  // B3: all z0 reads (epi0 + passM) done
    wb(z0, 1.f);                      // z0 <- Z2 (in-place over Z0)
    __syncthreads();                  // B4: Z2 visible
    pass(Lb, z0);                     // acc = L@Z2
    wb(z1, 2.f);                      // z1 <- S3 = 2L@Z2 (z1 dead since epi0 < B3)
    __syncthreads();                  // B5: S3 visible
    epi(z0, z1, wf[1]);               // accOut += Z2@W2 + S3@W3
    pass(Mb, z0);                     // acc = M2@Z2
    __syncthreads();                  // B6: all z0/z1 reads done
    wb(z0, 2.f);                      // z0 <- S4 = 2M2@Z2
    __syncthreads();                  // B7: S4 visible
    epi(z0, z0, wf[2]);               // accOut += S4@W4 (second-half weights zero)

    // ---------------- store via LDS (dense float4 bursts) ----------------
    // z1 dead (last read epi1, before B6). fbuf [bt][n][fo] fp32 = 65,536 B.
    float* fbuf = reinterpret_cast<float*>(z1);
    if (lr < 8) {
#pragma unroll
        for (int mi = 0; mi < 2; ++mi) {
            int n0 = (wave + mi * 16) * 16 + q * 4;
#pragma unroll
            for (int bt = 0; bt < BT; ++bt) {
#pragma unroll
                for (int r = 0; r < 4; ++r)
                    fbuf[(bt * BN + n0 + r) * FOUT + lr] = accOut[mi][bt][r] + bv;
            }
        }
    }
    __syncthreads();                  // B8: fbuf complete
    {
        const float4* fb4 = reinterpret_cast<const float4*>(fbuf);
        float4* o4 = reinterpret_cast<float4*>(out + (size_t)blockIdx.x * (BT * BN * FOUT));
#pragma unroll
        for (int i = 0; i < 4; ++i)
            o4[i * 1024 + tid] = fb4[i * 1024 + tid];
    }
}

// ---------------- v1 fallback (4-app recurrence), used if ws too small ----------------
template <bool LBF16>
__global__ __launch_bounds__(512, 2)
void cheb1_kernel(const float* __restrict__ x, const float* __restrict__ Lf,
                  const uint16_t* __restrict__ Lb, const float* __restrict__ W,
                  const float* __restrict__ bvec, float* __restrict__ out) {
    __shared__ uint16_t lds[2 * ZBUF];
    uint16_t* z0 = lds;
    uint16_t* z1 = lds + ZBUF;

    const int tid  = threadIdx.x;
    const int wave = tid >> 6;
    const int lane = tid & 63;
    const int lr   = lane & 15;
    const int q    = lane >> 4;

    const float4* x4 = reinterpret_cast<const float4*>(x + (size_t)blockIdx.x * (BT * BN * FIN));
    for (int s = 0; s < 2; ++s) {
        int a   = tid + s * 512;
        int f0g = a & 3;
        int n8  = (a >> 2) & 63;
        int bl  = a >> 8;
        int jb  = bl * 2048 + n8 * 32 + f0g;
        float4 v[8];
#pragma unroll
        for (int r = 0; r < 8; ++r) v[r] = x4[jb + r * 4];
        int cb = bl * 16 + f0g * 4;
        int nb = n8 * 8;
#pragma unroll
        for (int w = 0; w < 4; ++w) {
            frag_ab pk;
#pragma unroll
            for (int r = 0; r < 8; ++r)
                pk[r] = (short)f2bf(reinterpret_cast<const float*>(&v[r])[w]);
            *reinterpret_cast<frag_ab*>(&z0[(cb + w) * LDST + nb]) = pk;
        }
    }

    frag_ab wf[3];
#pragma unroll
    for (int p = 0; p < 3; ++p) {
        frag_ab t;
#pragma unroll
        for (int jj = 0; jj < 8; ++jj) {
            int k   = q * 8 + jj;
            int ki  = p * 2 + (k >> 4);
            int fin = k & 15;
            float val = (lr < 8 && ki < 5) ? W[ki * (FIN * FOUT) + fin * FOUT + lr] : 0.0f;
            t[jj] = (short)f2bf(val);
        }
        wf[p] = t;
    }
    const float bv = (lr < 8) ? bvec[lr] : 0.0f;

    frag_cd accOut[4][4] = {};

    auto loadA = [&](int mt, int ks) -> frag_ab {
        int row = mt * 16 + lr;
        int kb  = ks * 32 + q * 8;
        if constexpr (LBF16) {
            return *reinterpret_cast<const frag_ab*>(Lb + row * BN + kb);
        } else {
            const float4* p  = reinterpret_cast<const float4*>(Lf + row * BN + kb);
            float4 u0 = p[0], u1 = p[1];
            frag_ab t;
            t[0] = (short)f2bf(u0.x); t[1] = (short)f2bf(u0.y);
            t[2] = (short)f2bf(u0.z); t[3] = (short)f2bf(u0.w);
            t[4] = (short)f2bf(u1.x); t[5] = (short)f2bf(u1.y);
            t[6] = (short)f2bf(u1.z); t[7] = (short)f2bf(u1.w);
            return t;
        }
    };

    auto app = [&](const uint16_t* cur, uint16_t* dst, bool first) {
        frag_cd acc[4][4] = {};
        for (int ks = 0; ks < 16; ++ks) {
            frag_ab bfr[4];
#pragma unroll
            for (int ct = 0; ct < 4; ++ct)
                bfr[ct] = *reinterpret_cast<const frag_ab*>(
                    cur + (ct * 16 + lr) * LDST + ks * 32 + q * 8);
#pragma unroll
            for (int mi = 0; mi < 4; ++mi) {
                frag_ab a = loadA(wave + mi * 8, ks);
#pragma unroll
                for (int ct = 0; ct < 4; ++ct)
                    acc[mi][ct] = __builtin_amdgcn_mfma_f32_16x16x32_bf16(
                        a, bfr[ct], acc[mi][ct], 0, 0, 0);
            }
        }
#pragma unroll
        for (int mi = 0; mi < 4; ++mi) {
            int row0 = (wave + mi * 8) * 16 + q * 4;
#pragma unroll
            for (int ct = 0; ct < 4; ++ct) {
                uint16_t* dp = dst + (ct * 16 + lr) * LDST + row0;
                float pz[4] = {0.f, 0.f, 0.f, 0.f};
                if (!first) {
                    ushort4 pv = *reinterpret_cast<const ushort4*>(dp);
                    pz[0] = bf2f(pv.x); pz[1] = bf2f(pv.y);
                    pz[2] = bf2f(pv.z); pz[3] = bf2f(pv.w);
                }
                ushort4 nv;
                float v0 = acc[mi][ct][0], v1 = acc[mi][ct][1];
                float v2 = acc[mi][ct][2], v3 = acc[mi][ct][3];
                if (!first) {
                    v0 = 2.f * v0 - pz[0]; v1 = 2.f * v1 - pz[1];
                    v2 = 2.f * v2 - pz[2]; v3 = 2.f * v3 - pz[3];
                }
                nv.x = f2bf(v0); nv.y = f2bf(v1); nv.z = f2bf(v2); nv.w = f2bf(v3);
                *reinterpret_cast<ushort4*>(dp) = nv;
            }
        }
    };

    auto epi = [&](const uint16_t* bA, const uint16_t* bB, frag_ab wfr) {
        const uint16_t* base = (q < 2) ? bA : bB;
        int finb = (q & 1) * 8;
#pragma unroll
        for (int mi = 0; mi < 4; ++mi) {
            int n = (wave + mi * 8) * 16 + lr;
#pragma unroll
            for (int bt = 0; bt < 4; ++bt) {
                const uint16_t* pp = base + (bt * 16 + finb) * LDST + n;
                frag_ab afr;
#pragma unroll
                for (int jj = 0; jj < 8; ++jj) afr[jj] = (short)pp[jj * LDST];
                accOut[mi][bt] = __builtin_amdgcn_mfma_f32_16x16x32_bf16(
                    afr, wfr, accOut[mi][bt], 0, 0, 0);
            }
        }
    };

    __syncthreads();
    app(z0, z1, true);
    __syncthreads();
    epi(z0, z1, wf[0]);
    __syncthreads();
    app(z1, z0, false);
    __syncthreads();
    app(z0, z1, false);
    __syncthreads();
    epi(z0, z1, wf[1]);
    __syncthreads();
    app(z1, z0, false);
    __syncthreads();
    epi(z0, z0, wf[2]);

    if (lr < 8) {
        float* ob = out + (size_t)blockIdx.x * BT * BN * FOUT;
#pragma unroll
        for (int mi = 0; mi < 4; ++mi) {
            int row0 = (wave + mi * 8) * 16 + q * 4;
#pragma unroll
            for (int bt = 0; bt < 4; ++bt) {
                float* op = ob + bt * (BN * FOUT) + row0 * FOUT + lr;
                op[0 * FOUT] = accOut[mi][bt][0] + bv;
                op[1 * FOUT] = accOut[mi][bt][1] + bv;
                op[2 * FOUT] = accOut[mi][bt][2] + bv;
                op[3 * FOUT] = accOut[mi][bt][3] + bv;
            }
        }
    }
}

extern "C" void kernel_launch(void* const* d_in, const int* in_sizes, int n_in,
                              void* d_out, int out_size, void* d_ws, size_t ws_size,
                              hipStream_t stream) {
    const float* x  = (const float*)d_in[0];   // [1024,512,16]
    const float* Lf = (const float*)d_in[1];   // [512,512]
    const float* W  = (const float*)d_in[2];   // [5,16,8]
    const float* bv = (const float*)d_in[3];   // [8]
    float* out = (float*)d_out;                // [1024,512,8]

    const size_t matB = (size_t)BN * BN * sizeof(uint16_t);   // 512 KiB

    if (ws_size >= 2 * matB) {
        // Primary path: swizzled Lb = bf16(L), Mb = bf16(2L^2 - I), 1024-thr kernel.
        uint16_t* Lb = (uint16_t*)d_ws;
        uint16_t* Mb = Lb + (size_t)BN * BN;
        cvtL_swz<<<dim3(128), dim3(256), 0, stream>>>(Lf, Lb);
        m2comp<<<dim3(256), dim3(256), 0, stream>>>(Lf, Mb);
        cheb2_kernel<<<dim3(256), dim3(1024), 0, stream>>>(x, Lb, Mb, W, bv, out);
    } else if (ws_size >= matB) {
        uint16_t* Lb = (uint16_t*)d_ws;
        cvtL_rm<<<dim3(1024), dim3(256), 0, stream>>>(Lf, Lb);
        cheb1_kernel<true><<<dim3(256), dim3(512), 0, stream>>>(x, Lf, Lb, W, bv, out);
    } else {
        cheb1_kernel<false><<<dim3(256), dim3(512), 0, stream>>>(x, Lf, nullptr, W, bv, out);
    }
}

// Round 7
// 162.950 us; speedup vs baseline: 1.2146x; 1.0569x over previous
//
#include <hip/hip_runtime.h>
#include <cstdint>
#include <cstddef>

// ManualChebConv v7: single-GEMM reformulation.
//   P_k = T_k(L) precomputed (bf16, swizzled fragment layout, tiny GEMM chain)
//   Ycat[(k,m)][(b,fo)] = (x[b] @ W_k)[m,fo]   (bf16, 42 MB, written once)
//   out[n,(b,fo)] = sum_{k,m} P_k[n,m] * Ycat[(k,m),(b,fo)] + bias
// Rationale (post-mortems v1-v6): every prior version streams L/M2 per block
// = ~1 GB through L2 (the invariant explaining the 86us floor). This GEMM
// (M=512,N=8192,K=2560) cuts MFMA work 1.6x and operand volume ~3x, has no
// serial GEMM phases, and tiny accumulator state (32 VGPR) -> no spill.

typedef __attribute__((ext_vector_type(8))) short  frag_ab;  // 8 bf16
typedef __attribute__((ext_vector_type(4))) float  frag_cd;  // 4 fp32

constexpr int BN  = 512;
constexpr int FIN = 16;
constexpr int FOUT= 8;
constexpr int GK  = 5 * BN;            // 2560 = GEMM K
constexpr int LDST= BN + 8;            // v3 fallback LDS stride
constexpr int ZBUF= 64 * LDST;         // v3 fallback buffer (BT=4)

__device__ __forceinline__ uint16_t f2bf(float f) {
    uint32_t u = __builtin_bit_cast(uint32_t, f);
    u += 0x7FFFu + ((u >> 16) & 1u);
    return (uint16_t)(u >> 16);
}
__device__ __forceinline__ float bf2f(uint16_t h) {
    uint32_t u = ((uint32_t)h) << 16;
    return __builtin_bit_cast(float, u);
}

// ---- fragment layouts ----
// Pcat: [mt(32)][g(80)][lane(64)][elem(8)] u16, g = k*16 + kt  (kappa = g*32+...)
__device__ __forceinline__ size_t pfrag(int mt, int g, int lane) {
    return ((size_t)(mt * 80 + g) * 64 + lane) * 8;
}
__device__ __forceinline__ size_t pelem(int k, int row, int col) {
    return pfrag(row >> 4, k * 16 + (col >> 5),
                 ((col >> 3) & 3) * 16 + (row & 15)) + (col & 7);
}
// 16-kt standalone matrix (Llo, and v3-fallback Lb/Mb): [mt][kt(16)][lane][8]
__device__ __forceinline__ size_t lfrag16(int mt, int kt, int lane) {
    return ((size_t)(mt * 16 + kt) * 64 + lane) * 8;
}
__device__ __forceinline__ size_t aswz(int row, int k) {   // element in 16-kt layout
    return lfrag16(row >> 4, k >> 5, ((k >> 3) & 3) * 16 + (row & 15)) + (k & 7);
}

// ================= primary-path precompute kernels =================

// L -> Pcat k=1 block (bf16 hi) + Llo (bf16 residual), both fragment-order.
__global__ __launch_bounds__(256)
void cvtP(const float* __restrict__ Lf, uint16_t* __restrict__ Pcat,
          uint16_t* __restrict__ Llo) {
    int t = blockIdx.x * 256 + threadIdx.x;      // 128 blocks -> 32768
    int lane = t & 63, f = t >> 6;
    int mt = f >> 4, kt = f & 15;
    int row = mt * 16 + (lane & 15);
    int k0  = kt * 32 + (lane >> 4) * 8;
    const float4* p = reinterpret_cast<const float4*>(Lf + (size_t)row * BN + k0);
    float4 u0 = p[0], u1 = p[1];
    float v[8] = {u0.x, u0.y, u0.z, u0.w, u1.x, u1.y, u1.z, u1.w};
    frag_ab hi, lo;
#pragma unroll
    for (int j = 0; j < 8; ++j) {
        uint16_t h = f2bf(v[j]);
        hi[j] = (short)h;
        lo[j] = (short)f2bf(v[j] - bf2f(h));
    }
    *reinterpret_cast<frag_ab*>(Pcat + pfrag(mt, 16 + kt, lane)) = hi;  // k=1
    *reinterpret_cast<frag_ab*>(Llo + lfrag16(mt, kt, lane)) = lo;
}

// P0 = I in fragment order.
__global__ __launch_bounds__(256)
void pfill(uint16_t* __restrict__ Pcat) {
    int t = blockIdx.x * 256 + threadIdx.x;      // 128 blocks
    int lane = t & 63, f = t >> 6;
    int mt = f >> 4, kt = f & 15;
    int row = mt * 16 + (lane & 15);
    int kb  = kt * 32 + (lane >> 4) * 8;
    frag_ab o;
#pragma unroll
    for (int j = 0; j < 8; ++j) o[j] = (short)((row == kb + j) ? 0x3F80 : 0);
    *reinterpret_cast<frag_ab*>(Pcat + pfrag(mt, kt, lane)) = o;        // k=0
}

// P_dst = 2*L @ P_src - Sub.  L via hi/lo split; P symmetric -> the A-layout
// fragment at (mt=jt) doubles as the B-fragment (coalesced reads everywhere).
__global__ __launch_bounds__(256)
void pstep(uint16_t* __restrict__ Pcat, const uint16_t* __restrict__ Llo,
           int dstk, int srck, int subk) {
    int tid = threadIdx.x, wv = tid >> 6, lane = tid & 63;
    int lr = lane & 15, q = lane >> 4;
    int it = blockIdx.x * 4 + wv;                // 256 blocks -> 1024 tiles
    int to = it >> 5, jt = it & 31;
    frag_cd acc = {0.f, 0.f, 0.f, 0.f};
    for (int ks = 0; ks < 16; ++ks) {
        frag_ab ah = *reinterpret_cast<const frag_ab*>(Pcat + pfrag(to, 16 + ks, lane));
        frag_ab al = *reinterpret_cast<const frag_ab*>(Llo + lfrag16(to, ks, lane));
        frag_ab b  = *reinterpret_cast<const frag_ab*>(Pcat + pfrag(jt, srck * 16 + ks, lane));
        acc = __builtin_amdgcn_mfma_f32_16x16x32_bf16(ah, b, acc, 0, 0, 0);
        acc = __builtin_amdgcn_mfma_f32_16x16x32_bf16(al, b, acc, 0, 0, 0);
    }
#pragma unroll
    for (int r = 0; r < 4; ++r) {
        int row = to * 16 + q * 4 + r, col = jt * 16 + lr;
        float s = (subk < 0) ? ((row == col) ? 1.f : 0.f)
                             : bf2f(Pcat[pelem(subk, row, col)]);
        Pcat[pelem(dstk, row, col)] = f2bf(2.f * acc[r] - s);
    }
}

// Ycat[j = b*8+fo][kappa = k*512+m] = sum_f x[b,m,f] * W[k,f,fo]  (bf16)
// 512 blocks x 256 thr; 2 batches/block; thread owns m in {l, l+128, l+256, l+384}
// -> x loads are 64B-stride lane-contiguous, stores are lane-consecutive u16.
__global__ __launch_bounds__(256)
void ycat(const float* __restrict__ x, const float* __restrict__ W,
          uint16_t* __restrict__ Y) {
    int tid = threadIdx.x;
    int bb = tid >> 7, l = tid & 127;
    int b = blockIdx.x * 2 + bb;
    const float* xb = x + (size_t)b * (BN * FIN);
    float xf[4][16];
#pragma unroll
    for (int mm = 0; mm < 4; ++mm)
#pragma unroll
        for (int fi = 0; fi < 4; ++fi) {
            float4 u = *reinterpret_cast<const float4*>(xb + (size_t)(mm * 128 + l) * 16 + fi * 4);
            xf[mm][fi * 4 + 0] = u.x; xf[mm][fi * 4 + 1] = u.y;
            xf[mm][fi * 4 + 2] = u.z; xf[mm][fi * 4 + 3] = u.w;
        }
    uint16_t* yb = Y + (size_t)b * 8 * GK;
#pragma unroll
    for (int k = 0; k < 5; ++k) {
#pragma unroll
        for (int fo = 0; fo < 8; ++fo) {
            float a0 = 0.f, a1 = 0.f, a2 = 0.f, a3 = 0.f;
#pragma unroll
            for (int f = 0; f < 16; ++f) {
                float w = W[(k * 16 + f) * 8 + fo];   // wave-uniform -> scalarized
                a0 += xf[0][f] * w; a1 += xf[1][f] * w;
                a2 += xf[2][f] * w; a3 += xf[3][f] * w;
            }
            uint16_t* yr = yb + (size_t)fo * GK + k * 512 + l;
            yr[0]   = f2bf(a0); yr[128] = f2bf(a1);
            yr[256] = f2bf(a2); yr[384] = f2bf(a3);
        }
    }
}

// ================= the main GEMM =================
// C[n, j] = sum_kappa Pcat[n,kappa] * Ycat[kappa, j];  n in [m0,m0+128), j in [j0,j0+128)
// grid 256 = 4 Mtiles x 64 Jtiles (XCD-swizzled), 512 thr / 8 waves (2M x 4J),
// wave tile 64x32 -> acc 4x2 frags (32 VGPR). Double-buffered LDS, reg-staged.
__global__ __launch_bounds__(512, 2)
void chebgemm(const uint16_t* __restrict__ Pcat, const uint16_t* __restrict__ Y,
              const float* __restrict__ bvec, float* __restrict__ out) {
    __shared__ uint16_t lds[34816];              // 69,632 B
    uint16_t* a0 = lds;                          // A buf: 8 mt x 2 kt x 64 x 8
    uint16_t* a1 = lds + 8192;
    uint16_t* b0 = lds + 16384;                  // B buf: 128 rows x 72 (64+8 pad)
    uint16_t* b1 = lds + 25600;

    int bid = blockIdx.x;
    int wg  = (bid & 7) * 32 + (bid >> 3);       // bijective XCD swizzle (256=8x32)
    int mtB = wg >> 6;                           // 0..3
    int jtB = wg & 63;                           // 0..63
    int m0  = mtB * 128;
    int j0  = jtB * 128;

    int tid = threadIdx.x, wv = tid >> 6, lane = tid & 63;
    int lr = lane & 15, q = lane >> 4;
    int wm = wv >> 2, wj = wv & 3;

    frag_cd acc[4][2] = {};
    frag_ab rA[2], rB[2];

    auto loadA = [&](int c) {
#pragma unroll
        for (int s = 0; s < 2; ++s) {
            int idx = tid + s * 512;             // 0..1023
            int piece = idx >> 6, ln = idx & 63;
            int amt = piece >> 1, kk = piece & 1;
            rA[s] = *reinterpret_cast<const frag_ab*>(
                Pcat + pfrag(mtB * 8 + amt, c * 2 + kk, ln));
        }
    };
    auto loadB = [&](int c) {
#pragma unroll
        for (int s = 0; s < 2; ++s) {
            int idx = tid + s * 512;
            int jj = idx >> 3, c8 = idx & 7;
            rB[s] = *reinterpret_cast<const frag_ab*>(
                Y + (size_t)(j0 + jj) * GK + c * 64 + c8 * 8);
        }
    };
    auto writeS = [&](uint16_t* ab, uint16_t* bb) {
#pragma unroll
        for (int s = 0; s < 2; ++s) {
            int idx = tid + s * 512;
            *reinterpret_cast<frag_ab*>(ab + (size_t)idx * 8) = rA[s];
            int jj = idx >> 3, c8 = idx & 7;
            *reinterpret_cast<frag_ab*>(bb + (size_t)jj * 72 + c8 * 8) = rB[s];
        }
    };
    auto compute = [&](const uint16_t* ab, const uint16_t* bb) {
#pragma unroll
        for (int ksub = 0; ksub < 2; ++ksub) {
            frag_ab aF[4], bF[2];
#pragma unroll
            for (int mi = 0; mi < 4; ++mi)
                aF[mi] = *reinterpret_cast<const frag_ab*>(
                    ab + (size_t)(((wm * 4 + mi) * 2 + ksub) * 64 + lane) * 8);
#pragma unroll
            for (int cj = 0; cj < 2; ++cj)
                bF[cj] = *reinterpret_cast<const frag_ab*>(
                    bb + (size_t)(wj * 32 + cj * 16 + lr) * 72 + ksub * 32 + q * 8);
#pragma unroll
            for (int mi = 0; mi < 4; ++mi)
#pragma unroll
                for (int cj = 0; cj < 2; ++cj)
                    acc[mi][cj] = __builtin_amdgcn_mfma_f32_16x16x32_bf16(
                        aF[mi], bF[cj], acc[mi][cj], 0, 0, 0);
        }
    };

    loadA(0); loadB(0);
    writeS(a0, b0);
    __syncthreads();
    for (int c = 0; c < 40; ++c) {
        bool odd = (c & 1) != 0;
        const uint16_t* ap = odd ? a1 : a0;
        const uint16_t* bp = odd ? b1 : b0;
        uint16_t* an = odd ? a0 : a1;
        uint16_t* bn = odd ? b0 : b1;
        if (c < 39) { loadA(c + 1); loadB(c + 1); }   // issue early, land under MFMA
        compute(ap, bp);
        if (c < 39) writeS(an, bn);
        __syncthreads();
    }

    // epilogue: restage C tile (128x128 f32 = 64 KB) in LDS, write coalesced.
    float* fbuf = reinterpret_cast<float*>(lds);
#pragma unroll
    for (int mi = 0; mi < 4; ++mi)
#pragma unroll
        for (int cj = 0; cj < 2; ++cj) {
            int jl = wj * 32 + cj * 16 + lr;
#pragma unroll
            for (int r = 0; r < 4; ++r) {
                int nl = wm * 64 + mi * 16 + q * 4 + r;
                fbuf[nl * 128 + jl] = acc[mi][cj][r];
            }
        }
    __syncthreads();
    float4 bv0 = *reinterpret_cast<const float4*>(bvec);
    float4 bv1 = *(reinterpret_cast<const float4*>(bvec) + 1);
#pragma unroll
    for (int i = 0; i < 8; ++i) {
        int L = i * 2048 + tid * 4;              // covers 16384 floats
        int bb = L >> 10, r = L & 1023, nn = r >> 3, fo = r & 7;
        float4 v = *reinterpret_cast<const float4*>(fbuf + nn * 128 + bb * 8 + fo);
        float4 bias = (fo & 4) ? bv1 : bv0;
        v.x += bias.x; v.y += bias.y; v.z += bias.z; v.w += bias.w;
        *reinterpret_cast<float4*>(out + (size_t)(j0 / 8 + bb) * 4096
                                       + (size_t)(m0 + nn) * 8 + fo) = v;
    }
}

// ================= v3 fallback path (ws >= 1 MB) =================

__global__ __launch_bounds__(256)
void cvtL_swz(const float* __restrict__ Lf, uint16_t* __restrict__ Lb) {
    int t = blockIdx.x * 256 + threadIdx.x;
    int f = t >> 6, lane = t & 63;
    int mt = f >> 4, ks = f & 15;
    int row = mt * 16 + (lane & 15);
    int k0  = ks * 32 + (lane >> 4) * 8;
    const float4* p = reinterpret_cast<const float4*>(Lf + (size_t)row * BN + k0);
    float4 u0 = p[0], u1 = p[1];
    frag_ab o;
    o[0] = (short)f2bf(u0.x); o[1] = (short)f2bf(u0.y);
    o[2] = (short)f2bf(u0.z); o[3] = (short)f2bf(u0.w);
    o[4] = (short)f2bf(u1.x); o[5] = (short)f2bf(u1.y);
    o[6] = (short)f2bf(u1.z); o[7] = (short)f2bf(u1.w);
    *reinterpret_cast<frag_ab*>(Lb + (size_t)t * 8) = o;
}

__global__ __launch_bounds__(256)
void m2comp(const float* __restrict__ Lf, uint16_t* __restrict__ Mb) {
    const int tid = threadIdx.x;
    const int wv = tid >> 6, lane = tid & 63, lr = lane & 15, q = lane >> 4;
    const int i0 = (blockIdx.x >> 4) * 32 + (wv >> 1) * 16;
    const int j0 = (blockIdx.x & 15) * 32 + (wv & 1) * 16;
    frag_cd acc = {0.f, 0.f, 0.f, 0.f};
    const float* arow = Lf + (size_t)(i0 + lr) * BN;
    const float* brow = Lf + (size_t)(j0 + lr) * BN;
    for (int ks = 0; ks < 16; ++ks) {
        const int kb = ks * 32 + q * 8;
        const float4* ap = reinterpret_cast<const float4*>(arow + kb);
        const float4* bp = reinterpret_cast<const float4*>(brow + kb);
        float4 A0 = ap[0], A1 = ap[1], B0 = bp[0], B1 = bp[1];
        float av[8]  = {A0.x, A0.y, A0.z, A0.w, A1.x, A1.y, A1.z, A1.w};
        float bw[8]  = {B0.x, B0.y, B0.z, B0.w, B1.x, B1.y, B1.z, B1.w};
        frag_ab ah, al, bh, bl;
#pragma unroll
        for (int j = 0; j < 8; ++j) {
            uint16_t h = f2bf(av[j]);
            ah[j] = (short)h; al[j] = (short)f2bf(av[j] - bf2f(h));
            uint16_t g = f2bf(bw[j]);
            bh[j] = (short)g; bl[j] = (short)f2bf(bw[j] - bf2f(g));
        }
        acc = __builtin_amdgcn_mfma_f32_16x16x32_bf16(ah, bh, acc, 0, 0, 0);
        acc = __builtin_amdgcn_mfma_f32_16x16x32_bf16(ah, bl, acc, 0, 0, 0);
        acc = __builtin_amdgcn_mfma_f32_16x16x32_bf16(al, bh, acc, 0, 0, 0);
    }
#pragma unroll
    for (int r = 0; r < 4; ++r) {
        int i = i0 + q * 4 + r, j = j0 + lr;
        float v = 2.f * acc[r] - ((i == j) ? 1.f : 0.f);
        Mb[aswz(i, j)] = f2bf(v);
    }
}

__global__ __launch_bounds__(512, 2)
void cheb2_kernel(const float* __restrict__ x, const uint16_t* __restrict__ Lb,
                  const uint16_t* __restrict__ Mb, const float* __restrict__ W,
                  const float* __restrict__ bvec, float* __restrict__ out) {
    __shared__ uint16_t ldsb[2 * ZBUF];
    uint16_t* z0 = ldsb;
    uint16_t* z1 = ldsb + ZBUF;
    const int tid = threadIdx.x, wave = tid >> 6, lane = tid & 63;
    const int lr = lane & 15, q = lane >> 4;

    const float4* x4 = reinterpret_cast<const float4*>(x + (size_t)blockIdx.x * (4 * BN * FIN));
    for (int s = 0; s < 2; ++s) {
        int a = tid + s * 512;
        int f0g = a & 3, n8 = (a >> 2) & 63, bl = a >> 8;
        int jb = bl * 2048 + n8 * 32 + f0g;
        float4 v[8];
#pragma unroll
        for (int r = 0; r < 8; ++r) v[r] = x4[jb + r * 4];
        int cb = bl * 16 + f0g * 4, nb = n8 * 8;
#pragma unroll
        for (int w = 0; w < 4; ++w) {
            frag_ab pk;
#pragma unroll
            for (int r = 0; r < 8; ++r)
                pk[r] = (short)f2bf(reinterpret_cast<const float*>(&v[r])[w]);
            *reinterpret_cast<frag_ab*>(&z0[(cb + w) * LDST + nb]) = pk;
        }
    }
    frag_ab wf[3];
#pragma unroll
    for (int p = 0; p < 3; ++p) {
        frag_ab t;
#pragma unroll
        for (int jj = 0; jj < 8; ++jj) {
            int k = q * 8 + jj, ki = p * 2 + (k >> 4), fin = k & 15;
            float val = 0.0f;
            if (lr < 8) {
                int idx = fin * FOUT + lr;
                if      (ki == 0) val = W[idx] - W[4 * 128 + idx];
                else if (ki == 1) val = W[128 + idx] - W[3 * 128 + idx];
                else if (ki < 5)  val = W[ki * 128 + idx];
            }
            t[jj] = (short)f2bf(val);
        }
        wf[p] = t;
    }
    const float bv = (lr < 8) ? bvec[lr] : 0.0f;
    frag_cd accOut[4][4] = {};
    frag_cd acc1[4][4], acc2[4][4];

    auto round = [&](const uint16_t* cur) {
#pragma unroll
        for (int mi = 0; mi < 4; ++mi)
#pragma unroll
            for (int ct = 0; ct < 4; ++ct) {
                acc1[mi][ct] = (frag_cd){0.f, 0.f, 0.f, 0.f};
                acc2[mi][ct] = (frag_cd){0.f, 0.f, 0.f, 0.f};
            }
        for (int ks = 0; ks < 16; ++ks) {
            frag_ab bfr[4];
#pragma unroll
            for (int ct = 0; ct < 4; ++ct)
                bfr[ct] = *reinterpret_cast<const frag_ab*>(
                    cur + (ct * 16 + lr) * LDST + ks * 32 + q * 8);
#pragma unroll
            for (int mi = 0; mi < 4; ++mi) {
                frag_ab a = *reinterpret_cast<const frag_ab*>(
                    Lb + lfrag16(wave + mi * 8, ks, lane));
                frag_ab m = *reinterpret_cast<const frag_ab*>(
                    Mb + lfrag16(wave + mi * 8, ks, lane));
#pragma unroll
                for (int ct = 0; ct < 4; ++ct)
                    acc1[mi][ct] = __builtin_amdgcn_mfma_f32_16x16x32_bf16(
                        a, bfr[ct], acc1[mi][ct], 0, 0, 0);
#pragma unroll
                for (int ct = 0; ct < 4; ++ct)
                    acc2[mi][ct] = __builtin_amdgcn_mfma_f32_16x16x32_bf16(
                        m, bfr[ct], acc2[mi][ct], 0, 0, 0);
            }
        }
    };
    auto wb = [&](frag_cd (&acc)[4][4], uint16_t* dst, float scale) {
#pragma unroll
        for (int mi = 0; mi < 4; ++mi) {
            int row0 = (wave + mi * 8) * 16 + q * 4;
#pragma unroll
            for (int ct = 0; ct < 4; ++ct) {
                uint16_t* dp = dst + (ct * 16 + lr) * LDST + row0;
                ushort4 nv;
                nv.x = f2bf(scale * acc[mi][ct][0]); nv.y = f2bf(scale * acc[mi][ct][1]);
                nv.z = f2bf(scale * acc[mi][ct][2]); nv.w = f2bf(scale * acc[mi][ct][3]);
                *reinterpret_cast<ushort4*>(dp) = nv;
            }
        }
    };
    auto epi = [&](const uint16_t* bA, const uint16_t* bB, frag_ab wfr) {
        const uint16_t* base = (q < 2) ? bA : bB;
        int finb = (q & 1) * 8;
#pragma unroll
        for (int mi = 0; mi < 4; ++mi) {
            int n = (wave + mi * 8) * 16 + lr;
#pragma unroll
            for (int bt = 0; bt < 4; ++bt) {
                const uint16_t* pp = base + (bt * 16 + finb) * LDST + n;
                frag_ab afr;
#pragma unroll
                for (int jj = 0; jj < 8; ++jj) afr[jj] = (short)pp[jj * LDST];
                accOut[mi][bt] = __builtin_amdgcn_mfma_f32_16x16x32_bf16(
                    afr, wfr, accOut[mi][bt], 0, 0, 0);
            }
        }
    };

    __syncthreads();
    round(z0);
    wb(acc1, z1, 1.f);
    __syncthreads();
    epi(z0, z1, wf[0]);
    __syncthreads();
    wb(acc2, z0, 1.f);
    __syncthreads();
    round(z0);
    wb(acc1, z1, 2.f);
    __syncthreads();
    epi(z0, z1, wf[1]);
    __syncthreads();
    wb(acc2, z0, 2.f);
    __syncthreads();
    epi(z0, z0, wf[2]);

    float* fbuf = reinterpret_cast<float*>(z1);
    if (lr < 8) {
#pragma unroll
        for (int mi = 0; mi < 4; ++mi) {
            int n0 = (wave + mi * 8) * 16 + q * 4;
#pragma unroll
            for (int bt = 0; bt < 4; ++bt)
#pragma unroll
                for (int r = 0; r < 4; ++r)
                    fbuf[(bt * BN + n0 + r) * FOUT + lr] = accOut[mi][bt][r] + bv;
        }
    }
    __syncthreads();
    {
        const float4* fb4 = reinterpret_cast<const float4*>(fbuf);
        float4* o4 = reinterpret_cast<float4*>(out + (size_t)blockIdx.x * (4 * BN * FOUT));
#pragma unroll
        for (int i = 0; i < 8; ++i)
            o4[i * 512 + tid] = fb4[i * 512 + tid];
    }
}

// last-resort (no workspace): direct 4-app recurrence, fp32 L converted on the fly
__global__ __launch_bounds__(512, 2)
void cheb1_kernel(const float* __restrict__ x, const float* __restrict__ Lf,
                  const float* __restrict__ W, const float* __restrict__ bvec,
                  float* __restrict__ out) {
    __shared__ uint16_t ldsb[2 * ZBUF];
    uint16_t* z0 = ldsb;
    uint16_t* z1 = ldsb + ZBUF;
    const int tid = threadIdx.x, wave = tid >> 6, lane = tid & 63;
    const int lr = lane & 15, q = lane >> 4;
    const float4* x4 = reinterpret_cast<const float4*>(x + (size_t)blockIdx.x * (4 * BN * FIN));
    for (int s = 0; s < 2; ++s) {
        int a = tid + s * 512;
        int f0g = a & 3, n8 = (a >> 2) & 63, bl = a >> 8;
        int jb = bl * 2048 + n8 * 32 + f0g;
        float4 v[8];
#pragma unroll
        for (int r = 0; r < 8; ++r) v[r] = x4[jb + r * 4];
        int cb = bl * 16 + f0g * 4, nb = n8 * 8;
#pragma unroll
        for (int w = 0; w < 4; ++w) {
            frag_ab pk;
#pragma unroll
            for (int r = 0; r < 8; ++r)
                pk[r] = (short)f2bf(reinterpret_cast<const float*>(&v[r])[w]);
            *reinterpret_cast<frag_ab*>(&z0[(cb + w) * LDST + nb]) = pk;
        }
    }
    frag_ab wf[3];
#pragma unroll
    for (int p = 0; p < 3; ++p) {
        frag_ab t;
#pragma unroll
        for (int jj = 0; jj < 8; ++jj) {
            int k = q * 8 + jj, ki = p * 2 + (k >> 4), fin = k & 15;
            float val = (lr < 8 && ki < 5) ? W[ki * 128 + fin * FOUT + lr] : 0.0f;
            t[jj] = (short)f2bf(val);
        }
        wf[p] = t;
    }
    const float bv = (lr < 8) ? bvec[lr] : 0.0f;
    frag_cd accOut[4][4] = {};
    auto loadA = [&](int mt, int ks) -> frag_ab {
        const float4* p = reinterpret_cast<const float4*>(Lf + (size_t)(mt * 16 + lr) * BN + ks * 32 + q * 8);
        float4 u0 = p[0], u1 = p[1];
        frag_ab t;
        t[0] = (short)f2bf(u0.x); t[1] = (short)f2bf(u0.y);
        t[2] = (short)f2bf(u0.z); t[3] = (short)f2bf(u0.w);
        t[4] = (short)f2bf(u1.x); t[5] = (short)f2bf(u1.y);
        t[6] = (short)f2bf(u1.z); t[7] = (short)f2bf(u1.w);
        return t;
    };
    auto app = [&](const uint16_t* cur, uint16_t* dst, bool first) {
        frag_cd acc[4][4] = {};
        for (int ks = 0; ks < 16; ++ks) {
            frag_ab bfr[4];
#pragma unroll
            for (int ct = 0; ct < 4; ++ct)
                bfr[ct] = *reinterpret_cast<const frag_ab*>(
                    cur + (ct * 16 + lr) * LDST + ks * 32 + q * 8);
#pragma unroll
            for (int mi = 0; mi < 4; ++mi) {
                frag_ab a = loadA(wave + mi * 8, ks);
#pragma unroll
                for (int ct = 0; ct < 4; ++ct)
                    acc[mi][ct] = __builtin_amdgcn_mfma_f32_16x16x32_bf16(
                        a, bfr[ct], acc[mi][ct], 0, 0, 0);
            }
        }
#pragma unroll
        for (int mi = 0; mi < 4; ++mi) {
            int row0 = (wave + mi * 8) * 16 + q * 4;
#pragma unroll
            for (int ct = 0; ct < 4; ++ct) {
                uint16_t* dp = dst + (ct * 16 + lr) * LDST + row0;
                float pz[4] = {0.f, 0.f, 0.f, 0.f};
                if (!first) {
                    ushort4 pv = *reinterpret_cast<const ushort4*>(dp);
                    pz[0] = bf2f(pv.x); pz[1] = bf2f(pv.y);
                    pz[2] = bf2f(pv.z); pz[3] = bf2f(pv.w);
                }
                ushort4 nv;
                float v0 = acc[mi][ct][0], v1 = acc[mi][ct][1];
                float v2 = acc[mi][ct][2], v3 = acc[mi][ct][3];
                if (!first) { v0 = 2.f*v0-pz[0]; v1 = 2.f*v1-pz[1];
                              v2 = 2.f*v2-pz[2]; v3 = 2.f*v3-pz[3]; }
                nv.x = f2bf(v0); nv.y = f2bf(v1); nv.z = f2bf(v2); nv.w = f2bf(v3);
                *reinterpret_cast<ushort4*>(dp) = nv;
            }
        }
    };
    auto epi = [&](const uint16_t* bA, const uint16_t* bB, frag_ab wfr) {
        const uint16_t* base = (q < 2) ? bA : bB;
        int finb = (q & 1) * 8;
#pragma unroll
        for (int mi = 0; mi < 4; ++mi) {
            int n = (wave + mi * 8) * 16 + lr;
#pragma unroll
            for (int bt = 0; bt < 4; ++bt) {
                const uint16_t* pp = base + (bt * 16 + finb) * LDST + n;
                frag_ab afr;
#pragma unroll
                for (int jj = 0; jj < 8; ++jj) afr[jj] = (short)pp[jj * LDST];
                accOut[mi][bt] = __builtin_amdgcn_mfma_f32_16x16x32_bf16(
                    afr, wfr, accOut[mi][bt], 0, 0, 0);
            }
        }
    };
    __syncthreads();
    app(z0, z1, true);  __syncthreads();
    epi(z0, z1, wf[0]); __syncthreads();
    app(z1, z0, false); __syncthreads();
    app(z0, z1, false); __syncthreads();
    epi(z0, z1, wf[1]); __syncthreads();
    app(z1, z0, false); __syncthreads();
    epi(z0, z0, wf[2]);
    if (lr < 8) {
        float* ob = out + (size_t)blockIdx.x * 4 * BN * FOUT;
#pragma unroll
        for (int mi = 0; mi < 4; ++mi) {
            int row0 = (wave + mi * 8) * 16 + q * 4;
#pragma unroll
            for (int bt = 0; bt < 4; ++bt) {
                float* op = ob + bt * (BN * FOUT) + row0 * FOUT + lr;
                op[0] = accOut[mi][bt][0] + bv; op[FOUT] = accOut[mi][bt][1] + bv;
                op[2 * FOUT] = accOut[mi][bt][2] + bv; op[3 * FOUT] = accOut[mi][bt][3] + bv;
            }
        }
    }
}

extern "C" void kernel_launch(void* const* d_in, const int* in_sizes, int n_in,
                              void* d_out, int out_size, void* d_ws, size_t ws_size,
                              hipStream_t stream) {
    const float* x  = (const float*)d_in[0];   // [1024,512,16]
    const float* Lf = (const float*)d_in[1];   // [512,512]
    const float* W  = (const float*)d_in[2];   // [5,16,8]
    const float* bv = (const float*)d_in[3];   // [8]
    float* out = (float*)d_out;                // [1024,512,8]

    const size_t PCAT_B = (size_t)32 * 80 * 64 * 8 * 2;        // 2,621,440
    const size_t LLO_B  = (size_t)BN * BN * 2;                 //   524,288
    const size_t YC_B   = (size_t)8192 * GK * 2;               // 41,943,040
    const size_t matB   = (size_t)BN * BN * 2;

    if (ws_size >= PCAT_B + LLO_B + YC_B) {
        uint16_t* Pcat = (uint16_t*)d_ws;
        uint16_t* Llo  = Pcat + PCAT_B / 2;
        uint16_t* Yc   = Pcat + (PCAT_B + LLO_B) / 2;
        cvtP  <<<dim3(128), dim3(256), 0, stream>>>(Lf, Pcat, Llo);
        pfill <<<dim3(128), dim3(256), 0, stream>>>(Pcat);
        pstep <<<dim3(256), dim3(256), 0, stream>>>(Pcat, Llo, 2, 1, -1);
        pstep <<<dim3(256), dim3(256), 0, stream>>>(Pcat, Llo, 3, 2, 1);
        pstep <<<dim3(256), dim3(256), 0, stream>>>(Pcat, Llo, 4, 3, 2);
        ycat  <<<dim3(512), dim3(256), 0, stream>>>(x, W, Yc);
        chebgemm<<<dim3(256), dim3(512), 0, stream>>>(Pcat, Yc, bv, out);
    } else if (ws_size >= 2 * matB) {
        uint16_t* Lb = (uint16_t*)d_ws;
        uint16_t* Mb = Lb + (size_t)BN * BN;
        cvtL_swz<<<dim3(128), dim3(256), 0, stream>>>(Lf, Lb);
        m2comp  <<<dim3(256), dim3(256), 0, stream>>>(Lf, Mb);
        cheb2_kernel<<<dim3(256), dim3(512), 0, stream>>>(x, Lb, Mb, W, bv, out);
    } else {
        cheb1_kernel<<<dim3(256), dim3(512), 0, stream>>>(x, Lf, W, bv, out);
    }
}

// Round 8
// 150.929 us; speedup vs baseline: 1.3114x; 1.0796x over previous
//
#include <hip/hip_runtime.h>
#include <cstdint>
#include <cstddef>

// ManualChebConv v8: single-GEMM formulation, overhead-crushed.
//   Pcat holds P1..P4 = T_k(L) bf16 in A-fragment order (k=1..4, no identity).
//   Yf holds Ycat[(k,m)][(b,fo)] = (x@W_k) bf16 in B-fragment order (k=0..4).
//   out[n,j] = Y0[n,j] + sum_{g} Pcat[n,g]*Yf[g,j] + bias   (one flat GEMM,
//   M=512, N=8192, K=2048, identity term folded into epilogue).
// v8 changes (post-mortem v7): precompute chain 116us of the 163 total.
//   - P-chain 3 serial GEMMs -> 2 (P3=2*L*P2-L and P4=2*P2*P2-I in ONE kernel),
//     both at 2 waves/SIMD (512-thr blocks) instead of 1.
//   - ycat fused with L-conversion (7 launches -> 4).
//   - chebgemm: NO LDS staging / NO barriers in the K-loop. A and B fragments
//     are direct coalesced 1KB reads (Y pre-swizzled to B-fragment order);
//     per-kt working set 16KB -> L1 serves intra-block reuse. XCD j-grouping:
//     the 4 M-blocks of a j-tile co-resident on one XCD -> Y j-slice L2-hot.
// Workspace = 45,088,768 B, exactly v7's requirement (known to fit).

typedef __attribute__((ext_vector_type(8))) short  frag_ab;  // 8 bf16
typedef __attribute__((ext_vector_type(4))) float  frag_cd;  // 4 fp32

constexpr int BN  = 512;
constexpr int FIN = 16;
constexpr int FOUT= 8;
constexpr int GK  = 5 * BN;        // Y kappa width (k=0..4)
constexpr int PG  = 64;            // Pcat g width (k=1..4)
constexpr int LDST= BN + 8;        // fallback LDS stride
constexpr int ZBUF= 64 * LDST;

__device__ __forceinline__ uint16_t f2bf(float f) {
    uint32_t u = __builtin_bit_cast(uint32_t, f);
    u += 0x7FFFu + ((u >> 16) & 1u);
    return (uint16_t)(u >> 16);
}
__device__ __forceinline__ float bf2f(uint16_t h) {
    uint32_t u = ((uint32_t)h) << 16;
    return __builtin_bit_cast(float, u);
}

// Pcat: [mt(32)][g(64)][lane(64)][elem(8)], g = (k-1)*16 + kt
__device__ __forceinline__ size_t pfrag(int mt, int g, int lane) {
    return ((size_t)(mt * PG + g) * 64 + lane) * 8;
}
__device__ __forceinline__ size_t pelem(int k, int row, int col) {  // k in 1..4
    return pfrag(row >> 4, (k - 1) * 16 + (col >> 5),
                 ((col >> 3) & 3) * 16 + (row & 15)) + (col & 7);
}
// 16-g aux matrices (Llo, P2lo; also fallback Lb/Mb): [mt][kt(16)][lane][8]
__device__ __forceinline__ size_t lfrag16(int mt, int kt, int lane) {
    return ((size_t)(mt * 16 + kt) * 64 + lane) * 8;
}
__device__ __forceinline__ size_t aswz(int row, int k) {
    return lfrag16(row >> 4, k >> 5, ((k >> 3) & 3) * 16 + (row & 15)) + (k & 7);
}
// Yf: [jt16(512)][g(80)][lane][8], kappa = k*512+m = g*32 + (q*8+elem)
__device__ __forceinline__ size_t yfrag(int jt16, int g, int lane) {
    return ((size_t)(jt16 * 80 + g) * 64 + lane) * 8;
}

// ---------------- K1: fused Y build + L conversion ----------------
// blocks 0..2047: Yf; blocks 2048..2175: L -> Pcat(k=1) hi + Llo.
__global__ __launch_bounds__(256)
void prep(const float* __restrict__ x, const float* __restrict__ Lf,
          const float* __restrict__ W, uint16_t* __restrict__ Pcat,
          uint16_t* __restrict__ Llo, uint16_t* __restrict__ Yf) {
    int bid = blockIdx.x, tid = threadIdx.x;
    if (bid < 2048) {
        // one thread = one (j, m-octet): y[j][k*512+m0..+8] for k=0..4
        int t = bid * 256 + tid;                 // 0..524287
        int jlow = t & 15;
        int moct = (t >> 4) & 63;
        int jhi  = t >> 10;                      // jt16, 0..511
        int b  = jhi * 2 + (jlow >> 3);
        int fo = jlow & 7;
        int m0 = moct * 8;
        float wr[5][16];
#pragma unroll
        for (int k = 0; k < 5; ++k)
#pragma unroll
            for (int f = 0; f < 16; ++f)
                wr[k][f] = W[(k * 16 + f) * 8 + fo];
        float tmp[5][8];
        const float* xb = x + (size_t)b * (BN * FIN) + (size_t)m0 * FIN;
#pragma unroll
        for (int r = 0; r < 8; ++r) {
            float xr[16];
#pragma unroll
            for (int fi = 0; fi < 4; ++fi) {
                float4 u = *reinterpret_cast<const float4*>(xb + r * FIN + fi * 4);
                xr[fi * 4 + 0] = u.x; xr[fi * 4 + 1] = u.y;
                xr[fi * 4 + 2] = u.z; xr[fi * 4 + 3] = u.w;
            }
#pragma unroll
            for (int k = 0; k < 5; ++k) {
                float s = 0.f;
#pragma unroll
                for (int f = 0; f < 16; ++f) s += xr[f] * wr[k][f];
                tmp[k][r] = s;
            }
        }
#pragma unroll
        for (int k = 0; k < 5; ++k) {
            frag_ab o;
#pragma unroll
            for (int j = 0; j < 8; ++j) o[j] = (short)f2bf(tmp[k][j]);
            *reinterpret_cast<frag_ab*>(
                Yf + yfrag(jhi, k * 16 + (moct >> 2), (moct & 3) * 16 + jlow)) = o;
        }
    } else {
        // L hi/lo split into fragment order
        int t = (bid - 2048) * 256 + tid;        // 0..32767
        int lane = t & 63, f = t >> 6;
        int mt = f >> 4, kt = f & 15;
        int row = mt * 16 + (lane & 15);
        int k0  = kt * 32 + (lane >> 4) * 8;
        const float4* p = reinterpret_cast<const float4*>(Lf + (size_t)row * BN + k0);
        float4 u0 = p[0], u1 = p[1];
        float v[8] = {u0.x, u0.y, u0.z, u0.w, u1.x, u1.y, u1.z, u1.w};
        frag_ab hi, lo;
#pragma unroll
        for (int j = 0; j < 8; ++j) {
            uint16_t h = f2bf(v[j]);
            hi[j] = (short)h;
            lo[j] = (short)f2bf(v[j] - bf2f(h));
        }
        *reinterpret_cast<frag_ab*>(Pcat + pfrag(mt, kt, lane)) = hi;   // k=1
        *reinterpret_cast<frag_ab*>(Llo + lfrag16(mt, kt, lane)) = lo;
    }
}

// ---------------- K2: P2 = 2*L*L - I (hi/lo out) ----------------
// 1024 wave-tiles, 128 blocks x 8 waves (2 waves/SIMD on 128 CUs).
__global__ __launch_bounds__(512)
void p2k(uint16_t* __restrict__ Pcat, const uint16_t* __restrict__ Llo,
         uint16_t* __restrict__ P2lo) {
    int tid = threadIdx.x, wv = tid >> 6, lane = tid & 63;
    int lr = lane & 15, q = lane >> 4;
    int id = blockIdx.x * 8 + wv;                // 0..1023
    int to = id >> 5, jt = id & 31;
    frag_cd acc = {0.f, 0.f, 0.f, 0.f};
#pragma unroll
    for (int ks = 0; ks < 16; ++ks) {
        frag_ab ahi = *reinterpret_cast<const frag_ab*>(Pcat + pfrag(to, ks, lane));
        frag_ab alo = *reinterpret_cast<const frag_ab*>(Llo + lfrag16(to, ks, lane));
        frag_ab bhi = *reinterpret_cast<const frag_ab*>(Pcat + pfrag(jt, ks, lane));
        frag_ab blo = *reinterpret_cast<const frag_ab*>(Llo + lfrag16(jt, ks, lane));
        acc = __builtin_amdgcn_mfma_f32_16x16x32_bf16(ahi, bhi, acc, 0, 0, 0);
        acc = __builtin_amdgcn_mfma_f32_16x16x32_bf16(alo, bhi, acc, 0, 0, 0);
        acc = __builtin_amdgcn_mfma_f32_16x16x32_bf16(ahi, blo, acc, 0, 0, 0);
    }
#pragma unroll
    for (int r = 0; r < 4; ++r) {
        int row = to * 16 + q * 4 + r, col = jt * 16 + lr;
        float v = 2.f * acc[r] - ((row == col) ? 1.f : 0.f);
        uint16_t h = f2bf(v);
        Pcat[pelem(2, row, col)] = h;
        P2lo[aswz(row, col)] = f2bf(v - bf2f(h));
    }
}

// ---------------- K3: P3 = 2*L*P2 - L  and  P4 = 2*P2*P2 - I ----------------
// 2048 wave-tiles, 256 blocks x 8 waves (2 waves/SIMD, all CUs).
__global__ __launch_bounds__(512)
void p34k(uint16_t* __restrict__ Pcat, const uint16_t* __restrict__ Llo,
          const uint16_t* __restrict__ P2lo) {
    int tid = threadIdx.x, wv = tid >> 6, lane = tid & 63;
    int lr = lane & 15, q = lane >> 4;
    int id = blockIdx.x * 8 + wv;                // 0..2047
    bool isP3 = id < 1024;
    int id2 = isP3 ? id : id - 1024;
    int to = id2 >> 5, jt = id2 & 31;
    int agoff = isP3 ? 0 : 16;                   // A = L (g0..15) or P2 (g16..31)
    const uint16_t* aLo = isP3 ? Llo : P2lo;
    frag_cd acc = {0.f, 0.f, 0.f, 0.f};
#pragma unroll
    for (int ks = 0; ks < 16; ++ks) {
        frag_ab ahi = *reinterpret_cast<const frag_ab*>(Pcat + pfrag(to, agoff + ks, lane));
        frag_ab alo = *reinterpret_cast<const frag_ab*>(aLo + lfrag16(to, ks, lane));
        frag_ab bhi = *reinterpret_cast<const frag_ab*>(Pcat + pfrag(jt, 16 + ks, lane));
        frag_ab blo = *reinterpret_cast<const frag_ab*>(P2lo + lfrag16(jt, ks, lane));
        acc = __builtin_amdgcn_mfma_f32_16x16x32_bf16(ahi, bhi, acc, 0, 0, 0);
        acc = __builtin_amdgcn_mfma_f32_16x16x32_bf16(alo, bhi, acc, 0, 0, 0);
        acc = __builtin_amdgcn_mfma_f32_16x16x32_bf16(ahi, blo, acc, 0, 0, 0);
    }
#pragma unroll
    for (int r = 0; r < 4; ++r) {
        int row = to * 16 + q * 4 + r, col = jt * 16 + lr;
        if (isP3) {
            float sub = bf2f(Pcat[pelem(1, row, col)]) + bf2f(Llo[aswz(row, col)]);
            Pcat[pelem(3, row, col)] = f2bf(2.f * acc[r] - sub);
        } else {
            float sub = (row == col) ? 1.f : 0.f;
            Pcat[pelem(4, row, col)] = f2bf(2.f * acc[r] - sub);
        }
    }
}

// ---------------- K4: the GEMM (no LDS in loop) ----------------
// 256 blocks (1/CU), 512 thr / 8 waves (2M x 4J), 128x128 tile, K=2048.
// XCD grouping: the 4 M-blocks of one j-tile are consecutive on one XCD.
__global__ __launch_bounds__(512)
void chebgemm(const uint16_t* __restrict__ Pcat, const uint16_t* __restrict__ Yf,
              const float* __restrict__ bvec, float* __restrict__ out) {
    __shared__ float fbuf[16384];                // 64 KB epilogue stage
    int bid = blockIdx.x;
    int xcd = bid & 7, n = bid >> 3;             // n 0..31
    int jt  = xcd * 8 + (n >> 2);                // 0..63 (8 j-tiles per XCD)
    int mtB = n & 3;                             // 0..3
    int tid = threadIdx.x, wv = tid >> 6, lane = tid & 63;
    int lr = lane & 15, q = lane >> 4;
    int wm = wv >> 2, wj = wv & 3;

    frag_cd acc[4][2] = {};
#pragma unroll 2
    for (int kt = 0; kt < 64; ++kt) {
        frag_ab aF[4], bF[2];
#pragma unroll
        for (int mi = 0; mi < 4; ++mi)
            aF[mi] = *reinterpret_cast<const frag_ab*>(
                Pcat + pfrag(mtB * 8 + wm * 4 + mi, kt, lane));
#pragma unroll
        for (int cj = 0; cj < 2; ++cj)
            bF[cj] = *reinterpret_cast<const frag_ab*>(
                Yf + yfrag(jt * 8 + wj * 2 + cj, 16 + kt, lane));
#pragma unroll
        for (int mi = 0; mi < 4; ++mi)
#pragma unroll
            for (int cj = 0; cj < 2; ++cj)
                acc[mi][cj] = __builtin_amdgcn_mfma_f32_16x16x32_bf16(
                    aF[mi], bF[cj], acc[mi][cj], 0, 0, 0);
    }
    // identity (k=0) term + stage to LDS
#pragma unroll
    for (int mi = 0; mi < 4; ++mi)
#pragma unroll
        for (int cj = 0; cj < 2; ++cj) {
            int jt16 = jt * 8 + wj * 2 + cj;
#pragma unroll
            for (int r = 0; r < 4; ++r) {
                int nloc = wm * 64 + mi * 16 + q * 4 + r;   // 0..127
                int ng = mtB * 128 + nloc;                  // 0..511
                float y0 = bf2f(Yf[yfrag(jt16, ng >> 5, ((ng >> 3) & 3) * 16 + lr)
                                   + (ng & 7)]);
                fbuf[nloc * 128 + wj * 32 + cj * 16 + lr] = acc[mi][cj][r] + y0;
            }
        }
    __syncthreads();
    float4 bv0 = *reinterpret_cast<const float4*>(bvec);
    float4 bv1 = *(reinterpret_cast<const float4*>(bvec) + 1);
#pragma unroll
    for (int i = 0; i < 8; ++i) {
        int idx = i * 2048 + tid * 4;            // 16384 floats
        int bb = idx >> 10, r = idx & 1023, nn = r >> 3, fo = r & 7;
        float4 v = *reinterpret_cast<const float4*>(fbuf + nn * 128 + bb * 8 + fo);
        float4 bias = (fo & 4) ? bv1 : bv0;
        v.x += bias.x; v.y += bias.y; v.z += bias.z; v.w += bias.w;
        *reinterpret_cast<float4*>(out + (size_t)(jt * 16 + bb) * 4096
                                       + (size_t)(mtB * 128 + nn) * 8 + fo) = v;
    }
}

// ================= fallback paths (from v7, verified) =================

__global__ __launch_bounds__(256)
void cvtL_swz(const float* __restrict__ Lf, uint16_t* __restrict__ Lb) {
    int t = blockIdx.x * 256 + threadIdx.x;
    int f = t >> 6, lane = t & 63;
    int mt = f >> 4, ks = f & 15;
    int row = mt * 16 + (lane & 15);
    int k0  = ks * 32 + (lane >> 4) * 8;
    const float4* p = reinterpret_cast<const float4*>(Lf + (size_t)row * BN + k0);
    float4 u0 = p[0], u1 = p[1];
    frag_ab o;
    o[0] = (short)f2bf(u0.x); o[1] = (short)f2bf(u0.y);
    o[2] = (short)f2bf(u0.z); o[3] = (short)f2bf(u0.w);
    o[4] = (short)f2bf(u1.x); o[5] = (short)f2bf(u1.y);
    o[6] = (short)f2bf(u1.z); o[7] = (short)f2bf(u1.w);
    *reinterpret_cast<frag_ab*>(Lb + (size_t)t * 8) = o;
}

__global__ __launch_bounds__(256)
void m2comp(const float* __restrict__ Lf, uint16_t* __restrict__ Mb) {
    const int tid = threadIdx.x;
    const int wv = tid >> 6, lane = tid & 63, lr = lane & 15, q = lane >> 4;
    const int i0 = (blockIdx.x >> 4) * 32 + (wv >> 1) * 16;
    const int j0 = (blockIdx.x & 15) * 32 + (wv & 1) * 16;
    frag_cd acc = {0.f, 0.f, 0.f, 0.f};
    const float* arow = Lf + (size_t)(i0 + lr) * BN;
    const float* brow = Lf + (size_t)(j0 + lr) * BN;
    for (int ks = 0; ks < 16; ++ks) {
        const int kb = ks * 32 + q * 8;
        const float4* ap = reinterpret_cast<const float4*>(arow + kb);
        const float4* bp = reinterpret_cast<const float4*>(brow + kb);
        float4 A0 = ap[0], A1 = ap[1], B0 = bp[0], B1 = bp[1];
        float av[8] = {A0.x, A0.y, A0.z, A0.w, A1.x, A1.y, A1.z, A1.w};
        float bw[8] = {B0.x, B0.y, B0.z, B0.w, B1.x, B1.y, B1.z, B1.w};
        frag_ab ah, al, bh, bl;
#pragma unroll
        for (int j = 0; j < 8; ++j) {
            uint16_t h = f2bf(av[j]);
            ah[j] = (short)h; al[j] = (short)f2bf(av[j] - bf2f(h));
            uint16_t g = f2bf(bw[j]);
            bh[j] = (short)g; bl[j] = (short)f2bf(bw[j] - bf2f(g));
        }
        acc = __builtin_amdgcn_mfma_f32_16x16x32_bf16(ah, bh, acc, 0, 0, 0);
        acc = __builtin_amdgcn_mfma_f32_16x16x32_bf16(ah, bl, acc, 0, 0, 0);
        acc = __builtin_amdgcn_mfma_f32_16x16x32_bf16(al, bh, acc, 0, 0, 0);
    }
#pragma unroll
    for (int r = 0; r < 4; ++r) {
        int i = i0 + q * 4 + r, j = j0 + lr;
        float v = 2.f * acc[r] - ((i == j) ? 1.f : 0.f);
        Mb[aswz(i, j)] = f2bf(v);
    }
}

__global__ __launch_bounds__(512, 2)
void cheb2_kernel(const float* __restrict__ x, const uint16_t* __restrict__ Lb,
                  const uint16_t* __restrict__ Mb, const float* __restrict__ W,
                  const float* __restrict__ bvec, float* __restrict__ out) {
    __shared__ uint16_t ldsb[2 * ZBUF];
    uint16_t* z0 = ldsb;
    uint16_t* z1 = ldsb + ZBUF;
    const int tid = threadIdx.x, wave = tid >> 6, lane = tid & 63;
    const int lr = lane & 15, q = lane >> 4;

    const float4* x4 = reinterpret_cast<const float4*>(x + (size_t)blockIdx.x * (4 * BN * FIN));
    for (int s = 0; s < 2; ++s) {
        int a = tid + s * 512;
        int f0g = a & 3, n8 = (a >> 2) & 63, bl = a >> 8;
        int jb = bl * 2048 + n8 * 32 + f0g;
        float4 v[8];
#pragma unroll
        for (int r = 0; r < 8; ++r) v[r] = x4[jb + r * 4];
        int cb = bl * 16 + f0g * 4, nb = n8 * 8;
#pragma unroll
        for (int w = 0; w < 4; ++w) {
            frag_ab pk;
#pragma unroll
            for (int r = 0; r < 8; ++r)
                pk[r] = (short)f2bf(reinterpret_cast<const float*>(&v[r])[w]);
            *reinterpret_cast<frag_ab*>(&z0[(cb + w) * LDST + nb]) = pk;
        }
    }
    frag_ab wf[3];
#pragma unroll
    for (int p = 0; p < 3; ++p) {
        frag_ab t;
#pragma unroll
        for (int jj = 0; jj < 8; ++jj) {
            int k = q * 8 + jj, ki = p * 2 + (k >> 4), fin = k & 15;
            float val = 0.0f;
            if (lr < 8) {
                int idx = fin * FOUT + lr;
                if      (ki == 0) val = W[idx] - W[4 * 128 + idx];
                else if (ki == 1) val = W[128 + idx] - W[3 * 128 + idx];
                else if (ki < 5)  val = W[ki * 128 + idx];
            }
            t[jj] = (short)f2bf(val);
        }
        wf[p] = t;
    }
    const float bv = (lr < 8) ? bvec[lr] : 0.0f;
    frag_cd accOut[4][4] = {};
    frag_cd acc1[4][4], acc2[4][4];

    auto round = [&](const uint16_t* cur) {
#pragma unroll
        for (int mi = 0; mi < 4; ++mi)
#pragma unroll
            for (int ct = 0; ct < 4; ++ct) {
                acc1[mi][ct] = (frag_cd){0.f, 0.f, 0.f, 0.f};
                acc2[mi][ct] = (frag_cd){0.f, 0.f, 0.f, 0.f};
            }
        for (int ks = 0; ks < 16; ++ks) {
            frag_ab bfr[4];
#pragma unroll
            for (int ct = 0; ct < 4; ++ct)
                bfr[ct] = *reinterpret_cast<const frag_ab*>(
                    cur + (ct * 16 + lr) * LDST + ks * 32 + q * 8);
#pragma unroll
            for (int mi = 0; mi < 4; ++mi) {
                frag_ab a = *reinterpret_cast<const frag_ab*>(
                    Lb + lfrag16(wave + mi * 8, ks, lane));
                frag_ab m = *reinterpret_cast<const frag_ab*>(
                    Mb + lfrag16(wave + mi * 8, ks, lane));
#pragma unroll
                for (int ct = 0; ct < 4; ++ct)
                    acc1[mi][ct] = __builtin_amdgcn_mfma_f32_16x16x32_bf16(
                        a, bfr[ct], acc1[mi][ct], 0, 0, 0);
#pragma unroll
                for (int ct = 0; ct < 4; ++ct)
                    acc2[mi][ct] = __builtin_amdgcn_mfma_f32_16x16x32_bf16(
                        m, bfr[ct], acc2[mi][ct], 0, 0, 0);
            }
        }
    };
    auto wb = [&](frag_cd (&acc)[4][4], uint16_t* dst, float scale) {
#pragma unroll
        for (int mi = 0; mi < 4; ++mi) {
            int row0 = (wave + mi * 8) * 16 + q * 4;
#pragma unroll
            for (int ct = 0; ct < 4; ++ct) {
                uint16_t* dp = dst + (ct * 16 + lr) * LDST + row0;
                ushort4 nv;
                nv.x = f2bf(scale * acc[mi][ct][0]); nv.y = f2bf(scale * acc[mi][ct][1]);
                nv.z = f2bf(scale * acc[mi][ct][2]); nv.w = f2bf(scale * acc[mi][ct][3]);
                *reinterpret_cast<ushort4*>(dp) = nv;
            }
        }
    };
    auto epi = [&](const uint16_t* bA, const uint16_t* bB, frag_ab wfr) {
        const uint16_t* base = (q < 2) ? bA : bB;
        int finb = (q & 1) * 8;
#pragma unroll
        for (int mi = 0; mi < 4; ++mi) {
            int n = (wave + mi * 8) * 16 + lr;
#pragma unroll
            for (int bt = 0; bt < 4; ++bt) {
                const uint16_t* pp = base + (bt * 16 + finb) * LDST + n;
                frag_ab afr;
#pragma unroll
                for (int jj = 0; jj < 8; ++jj) afr[jj] = (short)pp[jj * LDST];
                accOut[mi][bt] = __builtin_amdgcn_mfma_f32_16x16x32_bf16(
                    afr, wfr, accOut[mi][bt], 0, 0, 0);
            }
        }
    };

    __syncthreads();
    round(z0);
    wb(acc1, z1, 1.f);
    __syncthreads();
    epi(z0, z1, wf[0]);
    __syncthreads();
    wb(acc2, z0, 1.f);
    __syncthreads();
    round(z0);
    wb(acc1, z1, 2.f);
    __syncthreads();
    epi(z0, z1, wf[1]);
    __syncthreads();
    wb(acc2, z0, 2.f);
    __syncthreads();
    epi(z0, z0, wf[2]);

    float* fbuf = reinterpret_cast<float*>(z1);
    if (lr < 8) {
#pragma unroll
        for (int mi = 0; mi < 4; ++mi) {
            int n0 = (wave + mi * 8) * 16 + q * 4;
#pragma unroll
            for (int bt = 0; bt < 4; ++bt)
#pragma unroll
                for (int r = 0; r < 4; ++r)
                    fbuf[(bt * BN + n0 + r) * FOUT + lr] = accOut[mi][bt][r] + bv;
        }
    }
    __syncthreads();
    {
        const float4* fb4 = reinterpret_cast<const float4*>(fbuf);
        float4* o4 = reinterpret_cast<float4*>(out + (size_t)blockIdx.x * (4 * BN * FOUT));
#pragma unroll
        for (int i = 0; i < 8; ++i)
            o4[i * 512 + tid] = fb4[i * 512 + tid];
    }
}

__global__ __launch_bounds__(512, 2)
void cheb1_kernel(const float* __restrict__ x, const float* __restrict__ Lf,
                  const float* __restrict__ W, const float* __restrict__ bvec,
                  float* __restrict__ out) {
    __shared__ uint16_t ldsb[2 * ZBUF];
    uint16_t* z0 = ldsb;
    uint16_t* z1 = ldsb + ZBUF;
    const int tid = threadIdx.x, wave = tid >> 6, lane = tid & 63;
    const int lr = lane & 15, q = lane >> 4;
    const float4* x4 = reinterpret_cast<const float4*>(x + (size_t)blockIdx.x * (4 * BN * FIN));
    for (int s = 0; s < 2; ++s) {
        int a = tid + s * 512;
        int f0g = a & 3, n8 = (a >> 2) & 63, bl = a >> 8;
        int jb = bl * 2048 + n8 * 32 + f0g;
        float4 v[8];
#pragma unroll
        for (int r = 0; r < 8; ++r) v[r] = x4[jb + r * 4];
        int cb = bl * 16 + f0g * 4, nb = n8 * 8;
#pragma unroll
        for (int w = 0; w < 4; ++w) {
            frag_ab pk;
#pragma unroll
            for (int r = 0; r < 8; ++r)
                pk[r] = (short)f2bf(reinterpret_cast<const float*>(&v[r])[w]);
            *reinterpret_cast<frag_ab*>(&z0[(cb + w) * LDST + nb]) = pk;
        }
    }
    frag_ab wf[3];
#pragma unroll
    for (int p = 0; p < 3; ++p) {
        frag_ab t;
#pragma unroll
        for (int jj = 0; jj < 8; ++jj) {
            int k = q * 8 + jj, ki = p * 2 + (k >> 4), fin = k & 15;
            float val = (lr < 8 && ki < 5) ? W[ki * 128 + fin * FOUT + lr] : 0.0f;
            t[jj] = (short)f2bf(val);
        }
        wf[p] = t;
    }
    const float bv = (lr < 8) ? bvec[lr] : 0.0f;
    frag_cd accOut[4][4] = {};
    auto loadA = [&](int mt, int ks) -> frag_ab {
        const float4* p = reinterpret_cast<const float4*>(Lf + (size_t)(mt * 16 + lr) * BN + ks * 32 + q * 8);
        float4 u0 = p[0], u1 = p[1];
        frag_ab t;
        t[0] = (short)f2bf(u0.x); t[1] = (short)f2bf(u0.y);
        t[2] = (short)f2bf(u0.z); t[3] = (short)f2bf(u0.w);
        t[4] = (short)f2bf(u1.x); t[5] = (short)f2bf(u1.y);
        t[6] = (short)f2bf(u1.z); t[7] = (short)f2bf(u1.w);
        return t;
    };
    auto app = [&](const uint16_t* cur, uint16_t* dst, bool first) {
        frag_cd acc[4][4] = {};
        for (int ks = 0; ks < 16; ++ks) {
            frag_ab bfr[4];
#pragma unroll
            for (int ct = 0; ct < 4; ++ct)
                bfr[ct] = *reinterpret_cast<const frag_ab*>(
                    cur + (ct * 16 + lr) * LDST + ks * 32 + q * 8);
#pragma unroll
            for (int mi = 0; mi < 4; ++mi) {
                frag_ab a = loadA(wave + mi * 8, ks);
#pragma unroll
                for (int ct = 0; ct < 4; ++ct)
                    acc[mi][ct] = __builtin_amdgcn_mfma_f32_16x16x32_bf16(
                        a, bfr[ct], acc[mi][ct], 0, 0, 0);
            }
        }
#pragma unroll
        for (int mi = 0; mi < 4; ++mi) {
            int row0 = (wave + mi * 8) * 16 + q * 4;
#pragma unroll
            for (int ct = 0; ct < 4; ++ct) {
                uint16_t* dp = dst + (ct * 16 + lr) * LDST + row0;
                float pz[4] = {0.f, 0.f, 0.f, 0.f};
                if (!first) {
                    ushort4 pv = *reinterpret_cast<const ushort4*>(dp);
                    pz[0] = bf2f(pv.x); pz[1] = bf2f(pv.y);
                    pz[2] = bf2f(pv.z); pz[3] = bf2f(pv.w);
                }
                ushort4 nv;
                float v0 = acc[mi][ct][0], v1 = acc[mi][ct][1];
                float v2 = acc[mi][ct][2], v3 = acc[mi][ct][3];
                if (!first) { v0 = 2.f*v0-pz[0]; v1 = 2.f*v1-pz[1];
                              v2 = 2.f*v2-pz[2]; v3 = 2.f*v3-pz[3]; }
                nv.x = f2bf(v0); nv.y = f2bf(v1); nv.z = f2bf(v2); nv.w = f2bf(v3);
                *reinterpret_cast<ushort4*>(dp) = nv;
            }
        }
    };
    auto epi = [&](const uint16_t* bA, const uint16_t* bB, frag_ab wfr) {
        const uint16_t* base = (q < 2) ? bA : bB;
        int finb = (q & 1) * 8;
#pragma unroll
        for (int mi = 0; mi < 4; ++mi) {
            int n = (wave + mi * 8) * 16 + lr;
#pragma unroll
            for (int bt = 0; bt < 4; ++bt) {
                const uint16_t* pp = base + (bt * 16 + finb) * LDST + n;
                frag_ab afr;
#pragma unroll
                for (int jj = 0; jj < 8; ++jj) afr[jj] = (short)pp[jj * LDST];
                accOut[mi][bt] = __builtin_amdgcn_mfma_f32_16x16x32_bf16(
                    afr, wfr, accOut[mi][bt], 0, 0, 0);
            }
        }
    };
    __syncthreads();
    app(z0, z1, true);  __syncthreads();
    epi(z0, z1, wf[0]); __syncthreads();
    app(z1, z0, false); __syncthreads();
    app(z0, z1, false); __syncthreads();
    epi(z0, z1, wf[1]); __syncthreads();
    app(z1, z0, false); __syncthreads();
    epi(z0, z0, wf[2]);
    if (lr < 8) {
        float* ob = out + (size_t)blockIdx.x * 4 * BN * FOUT;
#pragma unroll
        for (int mi = 0; mi < 4; ++mi) {
            int row0 = (wave + mi * 8) * 16 + q * 4;
#pragma unroll
            for (int bt = 0; bt < 4; ++bt) {
                float* op = ob + bt * (BN * FOUT) + row0 * FOUT + lr;
                op[0] = accOut[mi][bt][0] + bv; op[FOUT] = accOut[mi][bt][1] + bv;
                op[2 * FOUT] = accOut[mi][bt][2] + bv; op[3 * FOUT] = accOut[mi][bt][3] + bv;
            }
        }
    }
}

extern "C" void kernel_launch(void* const* d_in, const int* in_sizes, int n_in,
                              void* d_out, int out_size, void* d_ws, size_t ws_size,
                              hipStream_t stream) {
    const float* x  = (const float*)d_in[0];   // [1024,512,16]
    const float* Lf = (const float*)d_in[1];   // [512,512]
    const float* W  = (const float*)d_in[2];   // [5,16,8]
    const float* bv = (const float*)d_in[3];   // [8]
    float* out = (float*)d_out;                // [1024,512,8]

    const size_t PCAT_B = (size_t)32 * PG * 64 * 8 * 2;    //  2,097,152
    const size_t LLO_B  = (size_t)BN * BN * 2;             //    524,288
    const size_t P2LO_B = LLO_B;                           //    524,288
    const size_t YF_B   = (size_t)512 * 80 * 64 * 8 * 2;   // 41,943,040
    const size_t matB   = (size_t)BN * BN * 2;

    if (ws_size >= PCAT_B + LLO_B + P2LO_B + YF_B) {       // 45,088,768 (= v7 req)
        uint16_t* Pcat = (uint16_t*)d_ws;
        uint16_t* Llo  = Pcat + PCAT_B / 2;
        uint16_t* P2lo = Pcat + (PCAT_B + LLO_B) / 2;
        uint16_t* Yf   = Pcat + (PCAT_B + LLO_B + P2LO_B) / 2;
        prep    <<<dim3(2176), dim3(256), 0, stream>>>(x, Lf, W, Pcat, Llo, Yf);
        p2k     <<<dim3(128),  dim3(512), 0, stream>>>(Pcat, Llo, P2lo);
        p34k    <<<dim3(256),  dim3(512), 0, stream>>>(Pcat, Llo, P2lo);
        chebgemm<<<dim3(256),  dim3(512), 0, stream>>>(Pcat, Yf, bv, out);
    } else if (ws_size >= 2 * matB) {
        uint16_t* Lb = (uint16_t*)d_ws;
        uint16_t* Mb = Lb + (size_t)BN * BN;
        cvtL_swz<<<dim3(128), dim3(256), 0, stream>>>(Lf, Lb);
        m2comp  <<<dim3(256), dim3(256), 0, stream>>>(Lf, Mb);
        cheb2_kernel<<<dim3(256), dim3(512), 0, stream>>>(x, Lb, Mb, W, bv, out);
    } else {
        cheb1_kernel<<<dim3(256), dim3(512), 0, stream>>>(x, Lf, W, bv, out);
    }
}